// Round 19
// baseline (982.351 us; speedup 1.0000x reference)
//
#include <hip/hip_runtime.h>
#include <stdint.h>

#define TOK 8192
#define EMBD 1024
#define HIDD 4096
#define NEXP 8

typedef _Float16 f16;
typedef _Float16 f16x8 __attribute__((ext_vector_type(8)));
typedef _Float16 f16x4 __attribute__((ext_vector_type(4)));
typedef float f32x4 __attribute__((ext_vector_type(4)));
typedef unsigned short u16;
typedef unsigned short u16x4 __attribute__((ext_vector_type(4)));

// ---------------- static workspace arena ----------------
constexpr size_t OFF_X16   = 0;                                      // [TOK][EMBD] f16
constexpr size_t OFF_RW1T  = OFF_X16  + (size_t)TOK*EMBD*2;          // [HIDD][EMBD] f16
constexpr size_t OFF_W1T   = OFF_RW1T + (size_t)HIDD*EMBD*2;         // [E][HIDD][EMBD] f16
constexpr size_t OFF_W2T   = OFF_W1T  + (size_t)NEXP*HIDD*EMBD*2;    // [E][EMBD][HIDD] f16
constexpr size_t OFF_HR    = OFF_W2T  + (size_t)NEXP*EMBD*HIDD*2;    // [TOK][HIDD] f16
constexpr size_t OFF_HG    = OFF_HR   + (size_t)TOK*HIDD*2;          // [2T+256][HIDD] f16
constexpr size_t OFF_YG    = OFF_HG   + (size_t)(2*TOK+256)*HIDD*2;  // [2T+256][EMBD] f16
constexpr size_t OFF_XF    = OFF_YG   + (size_t)(2*TOK+256)*EMBD*2;  // [512][EMBD] f32
constexpr size_t OFF_HF    = OFF_XF   + 512UL*EMBD*4;                // [512][HIDD] f32
constexpr size_t OFF_KIDX  = OFF_HF   + 512UL*HIDD*4;                // [2T] int
constexpr size_t OFF_KW    = OFF_KIDX + 2UL*TOK*4;                   // [2T] f32
constexpr size_t OFF_RMAP  = OFF_KW   + 2UL*TOK*4;                   // [2T] int (token-slot -> grouped row)
constexpr size_t OFF_TMAP  = OFF_RMAP + 2UL*TOK*4;                   // [2T] int (grouped row -> token)
constexpr size_t OFF_FLAG  = OFF_TMAP + 2UL*TOK*4;                   // [512] int
constexpr size_t OFF_MISC  = OFF_FLAG + 512UL*4;                     // counts[8],offs[9]@8,cur[8]@20,nf@30
constexpr size_t OFF_RW2T  = OFF_MISC + 1024;                        // [8][HIDD] f16
constexpr size_t WS_TOTAL  = OFF_RW2T + (size_t)NEXP*HIDD*2;

__device__ __align__(1024) unsigned char g_ws[WS_TOTAL];

__device__ __forceinline__ u16 f2h(float f) {
  f16 h = (f16)f;
  return __builtin_bit_cast(u16, h);
}

__device__ __forceinline__ void async_cp16(const void* g, void* l) {
  __builtin_amdgcn_global_load_lds((const __attribute__((address_space(1))) void*)g,
                                   (__attribute__((address_space(3))) void*)l, 16, 0, 0);
}

// ---------------- small utility kernels ----------------
__global__ void k_init() {
  int* misc = (int*)(g_ws + OFF_MISC);
  if (threadIdx.x < 32) misc[threadIdx.x] = 0;
}

__global__ void k_cvt_x(const float* __restrict__ x) {
  u16* X16 = (u16*)(g_ws + OFF_X16);
  int i = (blockIdx.x * 256 + threadIdx.x) * 4;
  float4 v = *(const float4*)(x + i);
  u16x4 o;
  o[0] = f2h(v.x); o[1] = f2h(v.y); o[2] = f2h(v.z); o[3] = f2h(v.w);
  *(u16x4*)(X16 + i) = o;
}

// rw2 [HIDD][8] fp32 -> RW2T [8][HIDD] f16 (router GEMV vector-load layout)
__global__ void k_cvt_rw2(const float* __restrict__ rw2) {
  u16* RW2T = (u16*)(g_ws + OFF_RW2T);
  int h = blockIdx.x * 256 + threadIdx.x;  // 0..4095
  float4 a = *(const float4*)&rw2[(size_t)h * 8];
  float4 b = *(const float4*)&rw2[(size_t)h * 8 + 4];
  RW2T[0 * HIDD + h] = f2h(a.x);
  RW2T[1 * HIDD + h] = f2h(a.y);
  RW2T[2 * HIDD + h] = f2h(a.z);
  RW2T[3 * HIDD + h] = f2h(a.w);
  RW2T[4 * HIDD + h] = f2h(b.x);
  RW2T[5 * HIDD + h] = f2h(b.y);
  RW2T[6 * HIDD + h] = f2h(b.z);
  RW2T[7 * HIDD + h] = f2h(b.w);
}

// in: fp32 [R][C] row-major, out: f16 [C][R] row-major (per blockIdx.z matrix)
// Vectorized: float4 reads (16B/lane), u16x4 writes (8B/lane, 128B/wave coalesced).
__global__ void k_transpose(const float* __restrict__ in, size_t offOut, int R, int C) {
  u16* out = (u16*)(g_ws + offOut);
  __shared__ u16 t[64][72];  // row stride 144B: 8B-aligned, 2-way read aliasing
  int r0 = blockIdx.y * 64, c0 = blockIdx.x * 64;
  size_t mb = (size_t)blockIdx.z * R * C;
  in += mb; out += mb;
  int tid = threadIdx.x;
#pragma unroll
  for (int i = 0; i < 4; ++i) {
    int r = i * 16 + (tid >> 4);
    int c4 = (tid & 15) * 4;
    float4 v = *(const float4*)&in[(size_t)(r0 + r) * C + c0 + c4];
    u16x4 p;
    p[0] = f2h(v.x); p[1] = f2h(v.y); p[2] = f2h(v.z); p[3] = f2h(v.w);
    *(u16x4*)&t[r][c4] = p;
  }
  __syncthreads();
#pragma unroll
  for (int i = 0; i < 4; ++i) {
    int lin = i * 256 + tid;
    int cc = lin >> 4;            // 0..63 (out row)
    int rr0 = (lin & 15) * 4;     // 0..60 (out col block)
    u16x4 o;
    o[0] = t[rr0 + 0][cc];
    o[1] = t[rr0 + 1][cc];
    o[2] = t[rr0 + 2][cc];
    o[3] = t[rr0 + 3][cc];
    *(u16x4*)&out[(size_t)(c0 + cc) * R + r0 + rr0] = o;
  }
}

// ------- 256x256 MFMA GEMM: BK=64 double-buffered 2-phase (r17-proven structure) ----
// C[M][N](f16) = act(A[M][K] @ BT[N][K]^T + bias[N]); grouped via offs;
// INDIRECT: A row r read from token row tokmap[r] (ungrouped source).
// 512 threads = 8 waves (2M x 4N); BK=64; LDS 128KB (2 bufs x (A 32KB + B 32KB)).
// One vmcnt(0)+barrier per K-step: the ~1500cyc compute phase covers HBM latency.
// Swizzle: 16B slot' = slot ^ (row&7), applied on BOTH global-source chunk and
// LDS fragment read (within each 128B row -> staging coalescing preserved).
template <bool SILU, bool GROUPED, bool INDIRECT, int GN>
__global__ __launch_bounds__(512, 2) void gemm256(size_t offA, size_t offB,
                                                  const float* __restrict__ bias,
                                                  size_t offC, int Mfix, int N, int K) {
  const u16* A  = (const u16*)(g_ws + offA);
  const u16* BT = (const u16*)(g_ws + offB);
  u16* C = (u16*)(g_ws + offC);
  const int* offs = (const int*)(g_ws + OFF_MISC) + 8;
  const int* tokmap = (const int*)(g_ws + OFF_TMAP);

  // XCD-contiguous index (bijective; nwg % 8 == 0 for all our grids)
  int nx = gridDim.x, ny = gridDim.y;
  int nwg = nx * ny * gridDim.z;
  int flat = (blockIdx.z * ny + blockIdx.y) * nx + blockIdx.x;
  int cpx = nwg >> 3;
  int u = (flat & 7) * cpx + (flat >> 3);
  // decode u -> (bz, g, by, bxin): GN-wide bx supertile keeps B-group ~2MB L2-hot
  int bxin = u % GN;
  int t1 = u / GN;
  int by = t1 % ny;
  int t2 = t1 / ny;
  int nxg = nx / GN;
  int g = t2 % nxg;
  int bz = t2 / nxg;
  int bx = g * GN + bxin;

  int e = GROUPED ? bz : 0;
  int rbase = GROUPED ? offs[e] : 0;
  int Me = GROUPED ? (offs[e + 1] - rbase) : Mfix;
  int m0 = by * 256;
  if (m0 >= Me) return;
  int n0 = bx * 256;
  const u16* Be = BT + (size_t)e * N * K;
  const float* be = bias + (size_t)e * N;

  // LDS 128KB: A buf b at b*16384, B buf b at 32768 + b*16384 (u16 units).
  // Each buf = [256 rows][64 f16] (128B rows, 8x 16B slots). Epilogue reuses all as Cs.
  __shared__ __align__(128) u16 SM[65536];

  int tid = threadIdx.x;
  int lane = tid & 63, wid = tid >> 6;
  int wm = wid >> 2, wn = wid & 3;     // 2 x 4 wave grid
  int rsel = lane & 15;
  int rg = lane >> 4;                  // 0..3
  int sp0 = (rg ^ (rsel & 7)) * 8;     // swizzled slot base (k-slice 0); slice 1 = sp0 ^ 32

  // staging: q = i*512 + tid -> row = q>>3 (64 per i-step), chunk cnom = q&7;
  // global source chunk csrc = cnom ^ (row&7)  [row&7 == srow&7 for all i]
  int srow = tid >> 3;                 // 0..63
  int cnom = tid & 7;
  int csrc = (cnom ^ (srow & 7)) * 8;  // element offset within the row

  const u16* aP[4];
  const u16* bP[4];
#pragma unroll
  for (int i = 0; i < 4; ++i) {
    int r = m0 + i * 64 + srow;
    if (GROUPED) r = (r < Me) ? r : (Me - 1);
    if (INDIRECT) aP[i] = A + (size_t)tokmap[rbase + r] * K + csrc;
    else          aP[i] = A + (size_t)(rbase + r) * K + csrc;
    bP[i] = Be + (size_t)(n0 + i * 64 + srow) * K + csrc;
  }

#define STAGE(b, k0)                                                        \
  do {                                                                      \
    _Pragma("unroll") for (int i = 0; i < 4; ++i)                           \
      async_cp16(aP[i] + (k0), &SM[(b)*16384 + (i * 512 + tid) * 8]);       \
    _Pragma("unroll") for (int i = 0; i < 4; ++i)                           \
      async_cp16(bP[i] + (k0), &SM[32768 + (b)*16384 + (i * 512 + tid) * 8]); \
  } while (0)

#define COMPUTE(bb)                                                             \
  {                                                                             \
    const u16* Ab = &SM[(bb)*16384];                                            \
    const u16* Bb = &SM[32768 + (bb)*16384];                                    \
    _Pragma("unroll") for (int ks = 0; ks < 2; ++ks) {                          \
      int spo = sp0 ^ (ks << 5);                                                \
      f16x8 af[8], bf[4];                                                       \
      _Pragma("unroll") for (int i = 0; i < 8; ++i)                             \
        af[i] = *(const f16x8*)&Ab[wm * 8192 + i * 1024 + rsel * 64 + spo];     \
      _Pragma("unroll") for (int j = 0; j < 4; ++j)                             \
        bf[j] = *(const f16x8*)&Bb[wn * 4096 + j * 1024 + rsel * 64 + spo];     \
      _Pragma("unroll") for (int i = 0; i < 8; ++i)                             \
        _Pragma("unroll") for (int j = 0; j < 4; ++j)                           \
          acc[i][j] = __builtin_amdgcn_mfma_f32_16x16x32_f16(af[i], bf[j],      \
                                                             acc[i][j], 0, 0, 0); \
    }                                                                           \
  }

  f32x4 acc[8][4] = {};
  int nt = K >> 6;  // K-steps of 64

  STAGE(0, 0);
  asm volatile("s_waitcnt vmcnt(0)" ::: "memory");
  __builtin_amdgcn_s_barrier();

  int buf = 0;
  for (int t = 0; t < nt; ++t) {
    if (t + 1 < nt) STAGE(buf ^ 1, (t + 1) << 6);  // issue next tile FIRST
    COMPUTE(buf);
    asm volatile("s_waitcnt vmcnt(0)" ::: "memory");  // next tile landed
    __builtin_amdgcn_s_barrier();
    buf ^= 1;
  }
#undef COMPUTE
#undef STAGE

  // ---- epilogue: stage C-tile in LDS (reuse all 128KB = 256x256 f16), store coalesced ----
  u16* Cs = SM;
#pragma unroll
  for (int j = 0; j < 4; ++j) {
    int colL = wn * 64 + j * 16 + rsel;
    float bn = be[n0 + colL];
#pragma unroll
    for (int i = 0; i < 8; ++i) {
#pragma unroll
      for (int r = 0; r < 4; ++r) {
        int ml = wm * 128 + i * 16 + rg * 4 + r;
        float v = acc[i][j][r] + bn;
        if (SILU) v = v / (1.0f + __expf(-v));
        Cs[ml * 256 + colL] = f2h(v);
      }
    }
  }
  __syncthreads();
#pragma unroll
  for (int i = 0; i < 16; ++i) {
    int lin = i * 512 + tid;          // 8192 chunks of 16B
    int row = lin >> 5, sl = lin & 31;
    if (!GROUPED || (m0 + row < Me))
      *(uint4*)(C + (size_t)(rbase + m0 + row) * N + n0 + sl * 8) =
          *(const uint4*)&Cs[row * 256 + sl * 8];
  }
}

// ---------------- router logits + top2 + margin flagging (+ expert counting) ----
// rw2 consumed via RW2T [8][HIDD] f16: 16 vector loads/thread (was 128 scalar).
__global__ void k_router(const float* __restrict__ rb2, const float* __restrict__ x) {
  const u16* HR = (const u16*)(g_ws + OFF_HR);
  const u16* RW2T = (const u16*)(g_ws + OFF_RW2T);
  int* kidx = (int*)(g_ws + OFF_KIDX);
  float* kw = (float*)(g_ws + OFF_KW);
  int* flag = (int*)(g_ws + OFF_FLAG);
  float* XF = (float*)(g_ws + OFF_XF);
  int* misc = (int*)(g_ws + OFF_MISC);

  int t = blockIdx.x, tid = threadIdx.x;
  int lane = tid & 63, w = tid >> 6;
  float acc[8] = {};
  const u16* hrow = HR + (size_t)t * HIDD;
#pragma unroll
  for (int i = 0; i < 2; ++i) {
    int base = i * 2048 + tid * 8;
    f16x8 v = *(const f16x8*)&hrow[base];
    float hv[8];
#pragma unroll
    for (int jj = 0; jj < 8; ++jj) hv[jj] = (float)v[jj];
#pragma unroll
    for (int e2 = 0; e2 < 8; ++e2) {
      f16x8 wv = *(const f16x8*)&RW2T[e2 * HIDD + base];
#pragma unroll
      for (int jj = 0; jj < 8; ++jj) acc[e2] += hv[jj] * (float)wv[jj];
    }
  }
#pragma unroll
  for (int m = 1; m < 64; m <<= 1)
#pragma unroll
    for (int e2 = 0; e2 < 8; ++e2) acc[e2] += __shfl_xor(acc[e2], m);

  __shared__ float red[4][8];
  __shared__ int s_fi;
  if (lane == 0)
    for (int e2 = 0; e2 < 8; ++e2) red[w][e2] = acc[e2];
  if (tid == 0) s_fi = -1;
  __syncthreads();
  if (tid == 0) {
    float lg[8];
    for (int e2 = 0; e2 < 8; ++e2)
      lg[e2] = red[0][e2] + red[1][e2] + red[2][e2] + red[3][e2] + rb2[e2];
    int i1 = 0; float l1 = lg[0];
    for (int e2 = 1; e2 < 8; ++e2) if (lg[e2] > l1) { l1 = lg[e2]; i1 = e2; }
    int i2 = -1; float l2 = -3.4e38f;
    for (int e2 = 0; e2 < 8; ++e2) if (e2 != i1 && lg[e2] > l2) { l2 = lg[e2]; i2 = e2; }
    float l3 = -3.4e38f;
    for (int e2 = 0; e2 < 8; ++e2) if (e2 != i1 && e2 != i2 && lg[e2] > l3) l3 = lg[e2];
    float ex = __expf(l2 - l1);
    float inv = 1.0f / (1.0f + ex);
    kidx[2 * t] = i1; kidx[2 * t + 1] = i2;
    kw[2 * t] = inv;  kw[2 * t + 1] = ex * inv;
    atomicAdd(&misc[i1], 1);   // expert counting fused (was k_count)
    atomicAdd(&misc[i2], 1);
    if (l2 - l3 < 4e-3f) {  // near-tie: needs exact fp32 rescue
      int fi = atomicAdd(misc + 30, 1);
      if (fi < 512) { flag[fi] = t; s_fi = fi; }
    }
  }
  __syncthreads();
  int fi = s_fi;
  if (fi >= 0) {
    const float* xs = x + (size_t)t * EMBD;
    float* xd = XF + (size_t)fi * EMBD;
    int d = tid * 4;
    *(float4*)(xd + d) = *(const float4*)(xs + d);
  }
}

// exact fp32 router hidden for flagged tokens: HF = silu(XF @ rw1 + rb1)
__global__ __launch_bounds__(256) void k_flag_gemm(const float* __restrict__ rw1,
                                                   const float* __restrict__ rb1) {
  int* misc = (int*)(g_ws + OFF_MISC);
  int F = misc[30]; if (F > 512) F = 512;
  int m0 = blockIdx.y * 64;
  if (m0 >= F) return;
  int n0 = blockIdx.x * 64;
  const float* XF = (const float*)(g_ws + OFF_XF);
  float* HF = (float*)(g_ws + OFF_HF);
  __shared__ float As[64][17];
  __shared__ float Bs[16][65];
  int tid = threadIdx.x;
  float acc[4][4] = {};
  for (int k0 = 0; k0 < EMBD; k0 += 16) {
#pragma unroll
    for (int i = 0; i < 4; ++i) {
      int lin = i * 256 + tid;
      As[lin >> 4][lin & 15] = XF[(size_t)(m0 + (lin >> 4)) * EMBD + k0 + (lin & 15)];
      Bs[lin >> 6][lin & 63] = rw1[(size_t)(k0 + (lin >> 6)) * HIDD + n0 + (lin & 63)];
    }
    __syncthreads();
    int ty = tid >> 4, tx = tid & 15;
#pragma unroll
    for (int kk = 0; kk < 16; ++kk) {
      float a4[4], b4[4];
#pragma unroll
      for (int a = 0; a < 4; ++a) a4[a] = As[ty * 4 + a][kk];
#pragma unroll
      for (int b = 0; b < 4; ++b) b4[b] = Bs[kk][tx * 4 + b];
#pragma unroll
      for (int a = 0; a < 4; ++a)
#pragma unroll
        for (int b = 0; b < 4; ++b) acc[a][b] += a4[a] * b4[b];
    }
    __syncthreads();
  }
  int ty = tid >> 4, tx = tid & 15;
  for (int a = 0; a < 4; ++a)
    for (int b = 0; b < 4; ++b) {
      int n = n0 + tx * 4 + b;
      float v = acc[a][b] + rb1[n];
      v = v / (1.0f + __expf(-v));
      HF[(size_t)(m0 + ty * 4 + a) * HIDD + n] = v;
    }
}

// exact top-2 for flagged tokens; fixes kidx/kw and compensates expert counts
__global__ void k_flag_fix(const float* __restrict__ rw2, const float* __restrict__ rb2) {
  int* misc = (int*)(g_ws + OFF_MISC);
  int F = misc[30]; if (F > 512) F = 512;
  int fi = blockIdx.x; if (fi >= F) return;
  const int* flag = (const int*)(g_ws + OFF_FLAG);
  const float* HF = (const float*)(g_ws + OFF_HF);
  int* kidx = (int*)(g_ws + OFF_KIDX);
  float* kw = (float*)(g_ws + OFF_KW);
  int t = flag[fi];
  int tid = threadIdx.x, lane = tid & 63, w = tid >> 6;
  const float* h = HF + (size_t)fi * HIDD;
  float acc[8] = {};
  for (int i = 0; i < 16; ++i) {
    int hh = i * 256 + tid;
    float hv = h[hh];
    const float* r2 = rw2 + (size_t)hh * 8;
#pragma unroll
    for (int e2 = 0; e2 < 8; ++e2) acc[e2] += hv * r2[e2];
  }
#pragma unroll
  for (int m = 1; m < 64; m <<= 1)
#pragma unroll
    for (int e2 = 0; e2 < 8; ++e2) acc[e2] += __shfl_xor(acc[e2], m);
  __shared__ float red[4][8];
  if (lane == 0)
    for (int e2 = 0; e2 < 8; ++e2) red[w][e2] = acc[e2];
  __syncthreads();
  if (tid == 0) {
    float lg[8];
    for (int e2 = 0; e2 < 8; ++e2)
      lg[e2] = red[0][e2] + red[1][e2] + red[2][e2] + red[3][e2] + rb2[e2];
    int i1 = 0; float l1 = lg[0];
    for (int e2 = 1; e2 < 8; ++e2) if (lg[e2] > l1) { l1 = lg[e2]; i1 = e2; }
    int i2 = -1; float l2 = -3.4e38f;
    for (int e2 = 0; e2 < 8; ++e2) if (e2 != i1 && lg[e2] > l2) { l2 = lg[e2]; i2 = e2; }
    float ex = __expf(l2 - l1);
    float inv = 1.0f / (1.0f + ex);
    int o1 = kidx[2 * t], o2 = kidx[2 * t + 1];
    if (o1 != i1 || o2 != i2) {  // compensate fused counts
      atomicAdd(&misc[o1], -1); atomicAdd(&misc[o2], -1);
      atomicAdd(&misc[i1], 1);  atomicAdd(&misc[i2], 1);
    }
    kidx[2 * t] = i1; kidx[2 * t + 1] = i2;
    kw[2 * t] = inv;  kw[2 * t + 1] = ex * inv;
  }
}

__global__ void k_scan() {
  if (threadIdx.x == 0) {
    int* misc = (int*)(g_ws + OFF_MISC);
    int* counts = misc; int* offs = misc + 8; int* cur = misc + 20;
    offs[0] = 0;
    for (int e = 0; e < 8; ++e) { offs[e + 1] = offs[e] + counts[e]; cur[e] = offs[e]; }
  }
}

// map-only: slot s -> grouped row r (rowmap), grouped row r -> token (tokmap)
__global__ void k_build() {
  int s = blockIdx.x * 256 + threadIdx.x;
  if (s < 2 * TOK) {
    const int* kidx = (const int*)(g_ws + OFF_KIDX);
    int* rowmap = (int*)(g_ws + OFF_RMAP);
    int* tokmap = (int*)(g_ws + OFF_TMAP);
    int* misc = (int*)(g_ws + OFF_MISC);
    int e = kidx[s];
    int r = atomicAdd(&misc[20 + e], 1);
    rowmap[s] = r;
    tokmap[r] = s >> 1;
  }
}

__global__ void k_combine(float* __restrict__ out) {
  int t = blockIdx.x, tid = threadIdx.x;
  const int* rowmap = (const int*)(g_ws + OFF_RMAP);
  const float* kw = (const float*)(g_ws + OFF_KW);
  const u16* YG = (const u16*)(g_ws + OFF_YG);
  int r0 = rowmap[2 * t], r1 = rowmap[2 * t + 1];
  float w0 = kw[2 * t], w1 = kw[2 * t + 1];
  int d = tid * 4;
  f16x4 a = *(const f16x4*)(YG + (size_t)r0 * EMBD + d);
  f16x4 b = *(const f16x4*)(YG + (size_t)r1 * EMBD + d);
  float4 o;
  o.x = w0 * (float)a[0] + w1 * (float)b[0];
  o.y = w0 * (float)a[1] + w1 * (float)b[1];
  o.z = w0 * (float)a[2] + w1 * (float)b[2];
  o.w = w0 * (float)a[3] + w1 * (float)b[3];
  *(float4*)(out + (size_t)t * EMBD + d) = o;
}

// ---------------- launch ----------------
extern "C" void kernel_launch(void* const* d_in, const int* in_sizes, int n_in,
                              void* d_out, int out_size, void* d_ws, size_t ws_size,
                              hipStream_t stream) {
  const float* x   = (const float*)d_in[0];
  const float* rw1 = (const float*)d_in[1];
  const float* rb1 = (const float*)d_in[2];
  const float* rw2 = (const float*)d_in[3];
  const float* rb2 = (const float*)d_in[4];
  const float* w1  = (const float*)d_in[5];
  const float* b1  = (const float*)d_in[6];
  const float* w2  = (const float*)d_in[7];
  const float* b2  = (const float*)d_in[8];
  float* out = (float*)d_out;

  k_init<<<dim3(1), dim3(32), 0, stream>>>();
  k_cvt_x<<<dim3(TOK * EMBD / 1024), dim3(256), 0, stream>>>(x);
  k_cvt_rw2<<<dim3(HIDD / 256), dim3(256), 0, stream>>>(rw2);
  k_transpose<<<dim3(HIDD / 64, EMBD / 64, 1), dim3(256), 0, stream>>>(rw1, OFF_RW1T, EMBD, HIDD);
  k_transpose<<<dim3(HIDD / 64, EMBD / 64, 8), dim3(256), 0, stream>>>(w1, OFF_W1T, EMBD, HIDD);
  k_transpose<<<dim3(EMBD / 64, HIDD / 64, 8), dim3(256), 0, stream>>>(w2, OFF_W2T, HIDD, EMBD);
  // router GEMM1: [8192 x 4096 x 1024], GN=4 (2MB B-group at K=1024)
  gemm256<true, false, false, 4><<<dim3(HIDD / 256, TOK / 256, 1), dim3(512), 0, stream>>>(
      OFF_X16, OFF_RW1T, rb1, OFF_HR, TOK, HIDD, EMBD);
  k_router<<<dim3(TOK), dim3(256), 0, stream>>>(rb2, x);
  k_flag_gemm<<<dim3(HIDD / 64, 8), dim3(256), 0, stream>>>(rw1, rb1);
  k_flag_fix<<<dim3(512), dim3(256), 0, stream>>>(rw2, rb2);
  k_scan<<<dim3(1), dim3(1), 0, stream>>>();
  k_build<<<dim3(2 * TOK / 256), dim3(256), 0, stream>>>();
  // expert GEMM1: grouped [~16384 x 4096 x 1024], A gathered via tokmap, GN=4
  gemm256<true, true, true, 4><<<dim3(HIDD / 256, 2 * TOK / 256, 8), dim3(512), 0, stream>>>(
      OFF_X16, OFF_W1T, b1, OFF_HG, 0, HIDD, EMBD);
  // expert GEMM2: grouped [~16384 x 1024 x 4096], GN=1 (B-panel 2MB at K=4096)
  gemm256<false, true, false, 1><<<dim3(EMBD / 256, 2 * TOK / 256, 8), dim3(512), 0, stream>>>(
      OFF_HG, OFF_W2T, b2, OFF_YG, 0, EMBD, HIDD);
  k_combine<<<dim3(TOK), dim3(256), 0, stream>>>(out);
}

// Round 20
// 876.796 us; speedup vs baseline: 1.1204x; 1.1204x over previous
//
#include <hip/hip_runtime.h>
#include <stdint.h>

#define TOK 8192
#define EMBD 1024
#define HIDD 4096
#define NEXP 8

typedef _Float16 f16;
typedef _Float16 f16x8 __attribute__((ext_vector_type(8)));
typedef _Float16 f16x4 __attribute__((ext_vector_type(4)));
typedef float f32x4 __attribute__((ext_vector_type(4)));
typedef unsigned short u16;
typedef unsigned short u16x4 __attribute__((ext_vector_type(4)));

// ---------------- static workspace arena ----------------
constexpr size_t OFF_X16   = 0;                                      // [TOK][EMBD] f16
constexpr size_t OFF_RW1T  = OFF_X16  + (size_t)TOK*EMBD*2;          // [HIDD][EMBD] f16
constexpr size_t OFF_W1T   = OFF_RW1T + (size_t)HIDD*EMBD*2;         // [E][HIDD][EMBD] f16
constexpr size_t OFF_W2T   = OFF_W1T  + (size_t)NEXP*HIDD*EMBD*2;    // [E][EMBD][HIDD] f16
constexpr size_t OFF_HR    = OFF_W2T  + (size_t)NEXP*EMBD*HIDD*2;    // [TOK][HIDD] f16
constexpr size_t OFF_HG    = OFF_HR   + (size_t)TOK*HIDD*2;          // [2T+256][HIDD] f16
constexpr size_t OFF_YG    = OFF_HG   + (size_t)(2*TOK+256)*HIDD*2;  // [2T+256][EMBD] f16
constexpr size_t OFF_XF    = OFF_YG   + (size_t)(2*TOK+256)*EMBD*2;  // [512][EMBD] f32
constexpr size_t OFF_HF    = OFF_XF   + 512UL*EMBD*4;                // [512][HIDD] f32
constexpr size_t OFF_KIDX  = OFF_HF   + 512UL*HIDD*4;                // [2T] int
constexpr size_t OFF_KW    = OFF_KIDX + 2UL*TOK*4;                   // [2T] f32
constexpr size_t OFF_RMAP  = OFF_KW   + 2UL*TOK*4;                   // [2T] int (token-slot -> grouped row)
constexpr size_t OFF_TMAP  = OFF_RMAP + 2UL*TOK*4;                   // [2T] int (grouped row -> token)
constexpr size_t OFF_FLAG  = OFF_TMAP + 2UL*TOK*4;                   // [512] int
constexpr size_t OFF_MISC  = OFF_FLAG + 512UL*4;                     // counts[8],offs[9]@8,cur[8]@20,nf@30
constexpr size_t OFF_RW2T  = OFF_MISC + 1024;                        // [8][HIDD] f16
constexpr size_t WS_TOTAL  = OFF_RW2T + (size_t)NEXP*HIDD*2;

__device__ __align__(1024) unsigned char g_ws[WS_TOTAL];

__device__ __forceinline__ u16 f2h(float f) {
  f16 h = (f16)f;
  return __builtin_bit_cast(u16, h);
}

__device__ __forceinline__ void async_cp16(const void* g, void* l) {
  __builtin_amdgcn_global_load_lds((const __attribute__((address_space(1))) void*)g,
                                   (__attribute__((address_space(3))) void*)l, 16, 0, 0);
}

// ---------------- small utility kernels ----------------
__global__ void k_init() {
  int* misc = (int*)(g_ws + OFF_MISC);
  if (threadIdx.x < 32) misc[threadIdx.x] = 0;
}

__global__ void k_cvt_x(const float* __restrict__ x) {
  u16* X16 = (u16*)(g_ws + OFF_X16);
  int i = (blockIdx.x * 256 + threadIdx.x) * 4;
  float4 v = *(const float4*)(x + i);
  u16x4 o;
  o[0] = f2h(v.x); o[1] = f2h(v.y); o[2] = f2h(v.z); o[3] = f2h(v.w);
  *(u16x4*)(X16 + i) = o;
}

// rw2 [HIDD][8] fp32 -> RW2T [8][HIDD] f16 (router GEMV vector-load layout)
__global__ void k_cvt_rw2(const float* __restrict__ rw2) {
  u16* RW2T = (u16*)(g_ws + OFF_RW2T);
  int h = blockIdx.x * 256 + threadIdx.x;  // 0..4095
  float4 a = *(const float4*)&rw2[(size_t)h * 8];
  float4 b = *(const float4*)&rw2[(size_t)h * 8 + 4];
  RW2T[0 * HIDD + h] = f2h(a.x);
  RW2T[1 * HIDD + h] = f2h(a.y);
  RW2T[2 * HIDD + h] = f2h(a.z);
  RW2T[3 * HIDD + h] = f2h(a.w);
  RW2T[4 * HIDD + h] = f2h(b.x);
  RW2T[5 * HIDD + h] = f2h(b.y);
  RW2T[6 * HIDD + h] = f2h(b.z);
  RW2T[7 * HIDD + h] = f2h(b.w);
}

// in: fp32 [R][C] row-major, out: f16 [C][R] row-major (per blockIdx.z matrix)
// Vectorized: float4 reads (16B/lane), u16x4 writes (8B/lane, 128B/wave coalesced).
__global__ void k_transpose(const float* __restrict__ in, size_t offOut, int R, int C) {
  u16* out = (u16*)(g_ws + offOut);
  __shared__ u16 t[64][68];  // row stride 136B: 8B-aligned, bounded bank aliasing
  int r0 = blockIdx.y * 64, c0 = blockIdx.x * 64;
  size_t mb = (size_t)blockIdx.z * R * C;
  in += mb; out += mb;
  int tid = threadIdx.x;
#pragma unroll
  for (int i = 0; i < 4; ++i) {
    int r = i * 16 + (tid >> 4);
    int c4 = (tid & 15) * 4;
    float4 v = *(const float4*)&in[(size_t)(r0 + r) * C + c0 + c4];
    u16x4 p;
    p[0] = f2h(v.x); p[1] = f2h(v.y); p[2] = f2h(v.z); p[3] = f2h(v.w);
    *(u16x4*)&t[r][c4] = p;
  }
  __syncthreads();
#pragma unroll
  for (int i = 0; i < 4; ++i) {
    int lin = i * 256 + tid;
    int cc = lin >> 4;            // 0..63 (out row)
    int rr0 = (lin & 15) * 4;     // 0..60 (out col block)
    u16x4 o;
    o[0] = t[rr0 + 0][cc];
    o[1] = t[rr0 + 1][cc];
    o[2] = t[rr0 + 2][cc];
    o[3] = t[rr0 + 3][cc];
    *(u16x4*)&out[(size_t)(c0 + cc) * R + r0 + rr0] = o;
  }
}

// ------- 256x256 MFMA GEMM: BK=64 double-buffered 2-phase (r17-proven structure) ----
// C[M][N](f16) = act(A[M][K] @ BT[N][K]^T + bias[N]); grouped via offs;
// INDIRECT: A row r read from token row tokmap[r] (ungrouped source).
// 512 threads = 8 waves (2M x 4N); BK=64; LDS 128KB (2 bufs x (A 32KB + B 32KB)).
// One vmcnt(0)+barrier per K-step: the ~1500cyc compute phase covers HBM latency.
// Swizzle: 16B slot' = slot ^ (row&7), applied on BOTH global-source chunk and
// LDS fragment read (within each 128B row -> staging coalescing preserved).
template <bool SILU, bool GROUPED, bool INDIRECT, int GN>
__global__ __launch_bounds__(512, 2) void gemm256(size_t offA, size_t offB,
                                                  const float* __restrict__ bias,
                                                  size_t offC, int Mfix, int N, int K) {
  const u16* A  = (const u16*)(g_ws + offA);
  const u16* BT = (const u16*)(g_ws + offB);
  u16* C = (u16*)(g_ws + offC);
  const int* offs = (const int*)(g_ws + OFF_MISC) + 8;
  const int* tokmap = (const int*)(g_ws + OFF_TMAP);

  // XCD-contiguous index (bijective; nwg % 8 == 0 for all our grids)
  int nx = gridDim.x, ny = gridDim.y;
  int nwg = nx * ny * gridDim.z;
  int flat = (blockIdx.z * ny + blockIdx.y) * nx + blockIdx.x;
  int cpx = nwg >> 3;
  int u = (flat & 7) * cpx + (flat >> 3);
  // decode u -> (bz, g, by, bxin): GN-wide bx supertile keeps B-group ~2MB L2-hot
  int bxin = u % GN;
  int t1 = u / GN;
  int by = t1 % ny;
  int t2 = t1 / ny;
  int nxg = nx / GN;
  int g = t2 % nxg;
  int bz = t2 / nxg;
  int bx = g * GN + bxin;

  int e = GROUPED ? bz : 0;
  int rbase = GROUPED ? offs[e] : 0;
  int Me = GROUPED ? (offs[e + 1] - rbase) : Mfix;
  int m0 = by * 256;
  if (m0 >= Me) return;
  int n0 = bx * 256;
  const u16* Be = BT + (size_t)e * N * K;
  const float* be = bias + (size_t)e * N;

  // LDS 128KB: A buf b at b*16384, B buf b at 32768 + b*16384 (u16 units).
  // Each buf = [256 rows][64 f16] (128B rows, 8x 16B slots). Epilogue reuses all as Cs.
  __shared__ __align__(128) u16 SM[65536];

  int tid = threadIdx.x;
  int lane = tid & 63, wid = tid >> 6;
  int wm = wid >> 2, wn = wid & 3;     // 2 x 4 wave grid
  int rsel = lane & 15;
  int rg = lane >> 4;                  // 0..3
  int sp0 = (rg ^ (rsel & 7)) * 8;     // swizzled slot base (k-slice 0); slice 1 = sp0 ^ 32

  // staging: q = i*512 + tid -> row = q>>3 (64 per i-step), chunk cnom = q&7;
  // global source chunk csrc = cnom ^ (row&7)  [row&7 == srow&7 for all i]
  int srow = tid >> 3;                 // 0..63
  int cnom = tid & 7;
  int csrc = (cnom ^ (srow & 7)) * 8;  // element offset within the row

  const u16* aP[4];
  const u16* bP[4];
#pragma unroll
  for (int i = 0; i < 4; ++i) {
    int r = m0 + i * 64 + srow;
    if (GROUPED) r = (r < Me) ? r : (Me - 1);
    if (INDIRECT) aP[i] = A + (size_t)tokmap[rbase + r] * K + csrc;
    else          aP[i] = A + (size_t)(rbase + r) * K + csrc;
    bP[i] = Be + (size_t)(n0 + i * 64 + srow) * K + csrc;
  }

#define STAGE(b, k0)                                                        \
  do {                                                                      \
    _Pragma("unroll") for (int i = 0; i < 4; ++i)                           \
      async_cp16(aP[i] + (k0), &SM[(b)*16384 + (i * 512 + tid) * 8]);       \
    _Pragma("unroll") for (int i = 0; i < 4; ++i)                           \
      async_cp16(bP[i] + (k0), &SM[32768 + (b)*16384 + (i * 512 + tid) * 8]); \
  } while (0)

#define COMPUTE(bb)                                                             \
  {                                                                             \
    const u16* Ab = &SM[(bb)*16384];                                            \
    const u16* Bb = &SM[32768 + (bb)*16384];                                    \
    _Pragma("unroll") for (int ks = 0; ks < 2; ++ks) {                          \
      int spo = sp0 ^ (ks << 5);                                                \
      f16x8 af[8], bf[4];                                                       \
      _Pragma("unroll") for (int i = 0; i < 8; ++i)                             \
        af[i] = *(const f16x8*)&Ab[wm * 8192 + i * 1024 + rsel * 64 + spo];     \
      _Pragma("unroll") for (int j = 0; j < 4; ++j)                             \
        bf[j] = *(const f16x8*)&Bb[wn * 4096 + j * 1024 + rsel * 64 + spo];     \
      _Pragma("unroll") for (int i = 0; i < 8; ++i)                             \
        _Pragma("unroll") for (int j = 0; j < 4; ++j)                           \
          acc[i][j] = __builtin_amdgcn_mfma_f32_16x16x32_f16(af[i], bf[j],      \
                                                             acc[i][j], 0, 0, 0); \
    }                                                                           \
  }

  f32x4 acc[8][4] = {};
  int nt = K >> 6;  // K-steps of 64

  STAGE(0, 0);
  asm volatile("s_waitcnt vmcnt(0)" ::: "memory");
  __builtin_amdgcn_s_barrier();

  int buf = 0;
  for (int t = 0; t < nt; ++t) {
    if (t + 1 < nt) STAGE(buf ^ 1, (t + 1) << 6);  // issue next tile FIRST
    COMPUTE(buf);
    asm volatile("s_waitcnt vmcnt(0)" ::: "memory");  // next tile landed
    __builtin_amdgcn_s_barrier();
    buf ^= 1;
  }
#undef COMPUTE
#undef STAGE

  // ---- epilogue: stage C-tile in LDS (reuse all 128KB = 256x256 f16), store coalesced ----
  u16* Cs = SM;
#pragma unroll
  for (int j = 0; j < 4; ++j) {
    int colL = wn * 64 + j * 16 + rsel;
    float bn = be[n0 + colL];
#pragma unroll
    for (int i = 0; i < 8; ++i) {
#pragma unroll
      for (int r = 0; r < 4; ++r) {
        int ml = wm * 128 + i * 16 + rg * 4 + r;
        float v = acc[i][j][r] + bn;
        if (SILU) v = v / (1.0f + __expf(-v));
        Cs[ml * 256 + colL] = f2h(v);
      }
    }
  }
  __syncthreads();
#pragma unroll
  for (int i = 0; i < 16; ++i) {
    int lin = i * 512 + tid;          // 8192 chunks of 16B
    int row = lin >> 5, sl = lin & 31;
    if (!GROUPED || (m0 + row < Me))
      *(uint4*)(C + (size_t)(rbase + m0 + row) * N + n0 + sl * 8) =
          *(const uint4*)&Cs[row * 256 + sl * 8];
  }
}

// ---------------- router logits + top2 + margin flagging ----------------
// rw2 consumed via RW2T [8][HIDD] f16: 16 vector loads/thread (was 128 scalar).
__global__ void k_router(const float* __restrict__ rb2, const float* __restrict__ x) {
  const u16* HR = (const u16*)(g_ws + OFF_HR);
  const u16* RW2T = (const u16*)(g_ws + OFF_RW2T);
  int* kidx = (int*)(g_ws + OFF_KIDX);
  float* kw = (float*)(g_ws + OFF_KW);
  int* flag = (int*)(g_ws + OFF_FLAG);
  float* XF = (float*)(g_ws + OFF_XF);
  int* misc = (int*)(g_ws + OFF_MISC);

  int t = blockIdx.x, tid = threadIdx.x;
  int lane = tid & 63, w = tid >> 6;
  float acc[8] = {};
  const u16* hrow = HR + (size_t)t * HIDD;
#pragma unroll
  for (int i = 0; i < 2; ++i) {
    int base = i * 2048 + tid * 8;
    f16x8 v = *(const f16x8*)&hrow[base];
    float hv[8];
#pragma unroll
    for (int jj = 0; jj < 8; ++jj) hv[jj] = (float)v[jj];
#pragma unroll
    for (int e2 = 0; e2 < 8; ++e2) {
      f16x8 wv = *(const f16x8*)&RW2T[e2 * HIDD + base];
#pragma unroll
      for (int jj = 0; jj < 8; ++jj) acc[e2] += hv[jj] * (float)wv[jj];
    }
  }
#pragma unroll
  for (int m = 1; m < 64; m <<= 1)
#pragma unroll
    for (int e2 = 0; e2 < 8; ++e2) acc[e2] += __shfl_xor(acc[e2], m);

  __shared__ float red[4][8];
  __shared__ int s_fi;
  if (lane == 0)
    for (int e2 = 0; e2 < 8; ++e2) red[w][e2] = acc[e2];
  if (tid == 0) s_fi = -1;
  __syncthreads();
  if (tid == 0) {
    float lg[8];
    for (int e2 = 0; e2 < 8; ++e2)
      lg[e2] = red[0][e2] + red[1][e2] + red[2][e2] + red[3][e2] + rb2[e2];
    int i1 = 0; float l1 = lg[0];
    for (int e2 = 1; e2 < 8; ++e2) if (lg[e2] > l1) { l1 = lg[e2]; i1 = e2; }
    int i2 = -1; float l2 = -3.4e38f;
    for (int e2 = 0; e2 < 8; ++e2) if (e2 != i1 && lg[e2] > l2) { l2 = lg[e2]; i2 = e2; }
    float l3 = -3.4e38f;
    for (int e2 = 0; e2 < 8; ++e2) if (e2 != i1 && e2 != i2 && lg[e2] > l3) l3 = lg[e2];
    float ex = __expf(l2 - l1);
    float inv = 1.0f / (1.0f + ex);
    kidx[2 * t] = i1; kidx[2 * t + 1] = i2;
    kw[2 * t] = inv;  kw[2 * t + 1] = ex * inv;
    if (l2 - l3 < 4e-3f) {  // near-tie: needs exact fp32 rescue
      int fi = atomicAdd(misc + 30, 1);
      if (fi < 512) { flag[fi] = t; s_fi = fi; }
    }
  }
  __syncthreads();
  int fi = s_fi;
  if (fi >= 0) {
    const float* xs = x + (size_t)t * EMBD;
    float* xd = XF + (size_t)fi * EMBD;
    int d = tid * 4;
    *(float4*)(xd + d) = *(const float4*)(xs + d);
  }
}

// exact fp32 router hidden for flagged tokens: HF = silu(XF @ rw1 + rb1)
__global__ __launch_bounds__(256) void k_flag_gemm(const float* __restrict__ rw1,
                                                   const float* __restrict__ rb1) {
  int* misc = (int*)(g_ws + OFF_MISC);
  int F = misc[30]; if (F > 512) F = 512;
  int m0 = blockIdx.y * 64;
  if (m0 >= F) return;
  int n0 = blockIdx.x * 64;
  const float* XF = (const float*)(g_ws + OFF_XF);
  float* HF = (float*)(g_ws + OFF_HF);
  __shared__ float As[64][17];
  __shared__ float Bs[16][65];
  int tid = threadIdx.x;
  float acc[4][4] = {};
  for (int k0 = 0; k0 < EMBD; k0 += 16) {
#pragma unroll
    for (int i = 0; i < 4; ++i) {
      int lin = i * 256 + tid;
      As[lin >> 4][lin & 15] = XF[(size_t)(m0 + (lin >> 4)) * EMBD + k0 + (lin & 15)];
      Bs[lin >> 6][lin & 63] = rw1[(size_t)(k0 + (lin >> 6)) * HIDD + n0 + (lin & 63)];
    }
    __syncthreads();
    int ty = tid >> 4, tx = tid & 15;
#pragma unroll
    for (int kk = 0; kk < 16; ++kk) {
      float a4[4], b4[4];
#pragma unroll
      for (int a = 0; a < 4; ++a) a4[a] = As[ty * 4 + a][kk];
#pragma unroll
      for (int b = 0; b < 4; ++b) b4[b] = Bs[kk][tx * 4 + b];
#pragma unroll
      for (int a = 0; a < 4; ++a)
#pragma unroll
        for (int b = 0; b < 4; ++b) acc[a][b] += a4[a] * b4[b];
    }
    __syncthreads();
  }
  int ty = tid >> 4, tx = tid & 15;
  for (int a = 0; a < 4; ++a)
    for (int b = 0; b < 4; ++b) {
      int n = n0 + tx * 4 + b;
      float v = acc[a][b] + rb1[n];
      v = v / (1.0f + __expf(-v));
      HF[(size_t)(m0 + ty * 4 + a) * HIDD + n] = v;
    }
}

__global__ void k_flag_fix(const float* __restrict__ rw2, const float* __restrict__ rb2) {
  int* misc = (int*)(g_ws + OFF_MISC);
  int F = misc[30]; if (F > 512) F = 512;
  int fi = blockIdx.x; if (fi >= F) return;
  const int* flag = (const int*)(g_ws + OFF_FLAG);
  const float* HF = (const float*)(g_ws + OFF_HF);
  int* kidx = (int*)(g_ws + OFF_KIDX);
  float* kw = (float*)(g_ws + OFF_KW);
  int t = flag[fi];
  int tid = threadIdx.x, lane = tid & 63, w = tid >> 6;
  const float* h = HF + (size_t)fi * HIDD;
  float acc[8] = {};
  for (int i = 0; i < 16; ++i) {
    int hh = i * 256 + tid;
    float hv = h[hh];
    const float* r2 = rw2 + (size_t)hh * 8;
#pragma unroll
    for (int e2 = 0; e2 < 8; ++e2) acc[e2] += hv * r2[e2];
  }
#pragma unroll
  for (int m = 1; m < 64; m <<= 1)
#pragma unroll
    for (int e2 = 0; e2 < 8; ++e2) acc[e2] += __shfl_xor(acc[e2], m);
  __shared__ float red[4][8];
  if (lane == 0)
    for (int e2 = 0; e2 < 8; ++e2) red[w][e2] = acc[e2];
  __syncthreads();
  if (tid == 0) {
    float lg[8];
    for (int e2 = 0; e2 < 8; ++e2)
      lg[e2] = red[0][e2] + red[1][e2] + red[2][e2] + red[3][e2] + rb2[e2];
    int i1 = 0; float l1 = lg[0];
    for (int e2 = 1; e2 < 8; ++e2) if (lg[e2] > l1) { l1 = lg[e2]; i1 = e2; }
    int i2 = -1; float l2 = -3.4e38f;
    for (int e2 = 0; e2 < 8; ++e2) if (e2 != i1 && lg[e2] > l2) { l2 = lg[e2]; i2 = e2; }
    float ex = __expf(l2 - l1);
    float inv = 1.0f / (1.0f + ex);
    kidx[2 * t] = i1; kidx[2 * t + 1] = i2;
    kw[2 * t] = inv;  kw[2 * t + 1] = ex * inv;
  }
}

__global__ void k_count() {
  int idx = blockIdx.x * 256 + threadIdx.x;
  if (idx < 2 * TOK) {
    int* misc = (int*)(g_ws + OFF_MISC);
    const int* kidx = (const int*)(g_ws + OFF_KIDX);
    atomicAdd(&misc[kidx[idx]], 1);
  }
}

__global__ void k_scan() {
  if (threadIdx.x == 0) {
    int* misc = (int*)(g_ws + OFF_MISC);
    int* counts = misc; int* offs = misc + 8; int* cur = misc + 20;
    offs[0] = 0;
    for (int e = 0; e < 8; ++e) { offs[e + 1] = offs[e] + counts[e]; cur[e] = offs[e]; }
  }
}

// map-only: slot s -> grouped row r (rowmap), grouped row r -> token (tokmap)
__global__ void k_build() {
  int s = blockIdx.x * 256 + threadIdx.x;
  if (s < 2 * TOK) {
    const int* kidx = (const int*)(g_ws + OFF_KIDX);
    int* rowmap = (int*)(g_ws + OFF_RMAP);
    int* tokmap = (int*)(g_ws + OFF_TMAP);
    int* misc = (int*)(g_ws + OFF_MISC);
    int e = kidx[s];
    int r = atomicAdd(&misc[20 + e], 1);
    rowmap[s] = r;
    tokmap[r] = s >> 1;
  }
}

__global__ void k_combine(float* __restrict__ out) {
  int t = blockIdx.x, tid = threadIdx.x;
  const int* rowmap = (const int*)(g_ws + OFF_RMAP);
  const float* kw = (const float*)(g_ws + OFF_KW);
  const u16* YG = (const u16*)(g_ws + OFF_YG);
  int r0 = rowmap[2 * t], r1 = rowmap[2 * t + 1];
  float w0 = kw[2 * t], w1 = kw[2 * t + 1];
  int d = tid * 4;
  f16x4 a = *(const f16x4*)(YG + (size_t)r0 * EMBD + d);
  f16x4 b = *(const f16x4*)(YG + (size_t)r1 * EMBD + d);
  float4 o;
  o.x = w0 * (float)a[0] + w1 * (float)b[0];
  o.y = w0 * (float)a[1] + w1 * (float)b[1];
  o.z = w0 * (float)a[2] + w1 * (float)b[2];
  o.w = w0 * (float)a[3] + w1 * (float)b[3];
  *(float4*)(out + (size_t)t * EMBD + d) = o;
}

// ---------------- launch ----------------
extern "C" void kernel_launch(void* const* d_in, const int* in_sizes, int n_in,
                              void* d_out, int out_size, void* d_ws, size_t ws_size,
                              hipStream_t stream) {
  const float* x   = (const float*)d_in[0];
  const float* rw1 = (const float*)d_in[1];
  const float* rb1 = (const float*)d_in[2];
  const float* rw2 = (const float*)d_in[3];
  const float* rb2 = (const float*)d_in[4];
  const float* w1  = (const float*)d_in[5];
  const float* b1  = (const float*)d_in[6];
  const float* w2  = (const float*)d_in[7];
  const float* b2  = (const float*)d_in[8];
  float* out = (float*)d_out;

  k_init<<<dim3(1), dim3(32), 0, stream>>>();
  k_cvt_x<<<dim3(TOK * EMBD / 1024), dim3(256), 0, stream>>>(x);
  k_cvt_rw2<<<dim3(HIDD / 256), dim3(256), 0, stream>>>(rw2);
  k_transpose<<<dim3(HIDD / 64, EMBD / 64, 1), dim3(256), 0, stream>>>(rw1, OFF_RW1T, EMBD, HIDD);
  k_transpose<<<dim3(HIDD / 64, EMBD / 64, 8), dim3(256), 0, stream>>>(w1, OFF_W1T, EMBD, HIDD);
  k_transpose<<<dim3(EMBD / 64, HIDD / 64, 8), dim3(256), 0, stream>>>(w2, OFF_W2T, HIDD, EMBD);
  // router GEMM1: [8192 x 4096 x 1024], GN=4 (2MB B-group at K=1024)
  gemm256<true, false, false, 4><<<dim3(HIDD / 256, TOK / 256, 1), dim3(512), 0, stream>>>(
      OFF_X16, OFF_RW1T, rb1, OFF_HR, TOK, HIDD, EMBD);
  k_router<<<dim3(TOK), dim3(256), 0, stream>>>(rb2, x);
  k_flag_gemm<<<dim3(HIDD / 64, 8), dim3(256), 0, stream>>>(rw1, rb1);
  k_flag_fix<<<dim3(512), dim3(256), 0, stream>>>(rw2, rb2);
  k_count<<<dim3(2 * TOK / 256), dim3(256), 0, stream>>>();
  k_scan<<<dim3(1), dim3(1), 0, stream>>>();
  k_build<<<dim3(2 * TOK / 256), dim3(256), 0, stream>>>();
  // expert GEMM1: grouped [~16384 x 4096 x 1024], A gathered via tokmap, GN=4
  gemm256<true, true, true, 4><<<dim3(HIDD / 256, 2 * TOK / 256, 8), dim3(512), 0, stream>>>(
      OFF_X16, OFF_W1T, b1, OFF_HG, 0, HIDD, EMBD);
  // expert GEMM2: grouped [~16384 x 1024 x 4096], GN=1 (B-panel 2MB at K=4096)
  gemm256<false, true, false, 1><<<dim3(EMBD / 256, 2 * TOK / 256, 8), dim3(512), 0, stream>>>(
      OFF_HG, OFF_W2T, b2, OFF_YG, 0, EMBD, HIDD);
  k_combine<<<dim3(TOK), dim3(256), 0, stream>>>(out);
}

// Round 21
// 820.833 us; speedup vs baseline: 1.1968x; 1.0682x over previous
//
#include <hip/hip_runtime.h>
#include <stdint.h>

#define TOK 8192
#define EMBD 1024
#define HIDD 4096
#define NEXP 8

typedef _Float16 f16;
typedef _Float16 f16x8 __attribute__((ext_vector_type(8)));
typedef _Float16 f16x4 __attribute__((ext_vector_type(4)));
typedef float f32x4 __attribute__((ext_vector_type(4)));
typedef unsigned short u16;
typedef unsigned short u16x4 __attribute__((ext_vector_type(4)));

// ---------------- static workspace arena ----------------
constexpr size_t OFF_X16   = 0;                                      // [TOK][EMBD] f16
constexpr size_t OFF_RW1T  = OFF_X16  + (size_t)TOK*EMBD*2;          // [HIDD][EMBD] f16
constexpr size_t OFF_W1T   = OFF_RW1T + (size_t)HIDD*EMBD*2;         // [E][HIDD][EMBD] f16
constexpr size_t OFF_W2T   = OFF_W1T  + (size_t)NEXP*HIDD*EMBD*2;    // [E][EMBD][HIDD] f16
constexpr size_t OFF_HR    = OFF_W2T  + (size_t)NEXP*EMBD*HIDD*2;    // [TOK][HIDD] f16
constexpr size_t OFF_HG    = OFF_HR   + (size_t)TOK*HIDD*2;          // [2T+256][HIDD] f16
constexpr size_t OFF_YG    = OFF_HG   + (size_t)(2*TOK+256)*HIDD*2;  // [2T+256][EMBD] f16
constexpr size_t OFF_XF    = OFF_YG   + (size_t)(2*TOK+256)*EMBD*2;  // [512][EMBD] f32
constexpr size_t OFF_HF    = OFF_XF   + 512UL*EMBD*4;                // [512][HIDD] f32
constexpr size_t OFF_KIDX  = OFF_HF   + 512UL*HIDD*4;                // [2T] int
constexpr size_t OFF_KW    = OFF_KIDX + 2UL*TOK*4;                   // [2T] f32
constexpr size_t OFF_RMAP  = OFF_KW   + 2UL*TOK*4;                   // [2T] int (token-slot -> grouped row)
constexpr size_t OFF_TMAP  = OFF_RMAP + 2UL*TOK*4;                   // [2T] int (grouped row -> token)
constexpr size_t OFF_FLAG  = OFF_TMAP + 2UL*TOK*4;                   // [512] int
constexpr size_t OFF_MISC  = OFF_FLAG + 512UL*4;                     // counts[8],offs[9]@8,cur[8]@20,nf@30
constexpr size_t OFF_RW2T  = OFF_MISC + 1024;                        // [8][HIDD] f16
constexpr size_t WS_TOTAL  = OFF_RW2T + (size_t)NEXP*HIDD*2;

__device__ __align__(1024) unsigned char g_ws[WS_TOTAL];

__device__ __forceinline__ u16 f2h(float f) {
  f16 h = (f16)f;
  return __builtin_bit_cast(u16, h);
}

__device__ __forceinline__ void async_cp16(const void* g, void* l) {
  __builtin_amdgcn_global_load_lds((const __attribute__((address_space(1))) void*)g,
                                   (__attribute__((address_space(3))) void*)l, 16, 0, 0);
}

// ---------------- fused prep: x->f16, rw2 transpose->f16, misc init ----------------
// blocks [0, TOK*EMBD/1024): cvt x; next HIDD/256 blocks: cvt rw2; last block: init.
__global__ void k_prep(const float* __restrict__ x, const float* __restrict__ rw2) {
  int b = blockIdx.x, tid = threadIdx.x;
  constexpr int NBX = TOK * EMBD / 1024;
  if (b < NBX) {
    u16* X16 = (u16*)(g_ws + OFF_X16);
    int i = (b * 256 + tid) * 4;
    float4 v = *(const float4*)(x + i);
    u16x4 o;
    o[0] = f2h(v.x); o[1] = f2h(v.y); o[2] = f2h(v.z); o[3] = f2h(v.w);
    *(u16x4*)(X16 + i) = o;
  } else if (b < NBX + HIDD / 256) {
    u16* RW2T = (u16*)(g_ws + OFF_RW2T);
    int h = (b - NBX) * 256 + tid;  // 0..4095
    float4 a = *(const float4*)&rw2[(size_t)h * 8];
    float4 bb = *(const float4*)&rw2[(size_t)h * 8 + 4];
    RW2T[0 * HIDD + h] = f2h(a.x);
    RW2T[1 * HIDD + h] = f2h(a.y);
    RW2T[2 * HIDD + h] = f2h(a.z);
    RW2T[3 * HIDD + h] = f2h(a.w);
    RW2T[4 * HIDD + h] = f2h(bb.x);
    RW2T[5 * HIDD + h] = f2h(bb.y);
    RW2T[6 * HIDD + h] = f2h(bb.z);
    RW2T[7 * HIDD + h] = f2h(bb.w);
  } else {
    if (tid < 32) ((int*)(g_ws + OFF_MISC))[tid] = 0;
  }
}

// in: fp32 [R][C] row-major, out: f16 [C][R] row-major (per blockIdx.z matrix)
// Vectorized: float4 reads (16B/lane), u16x4 writes (8B/lane, 128B/wave coalesced).
__global__ void k_transpose(const float* __restrict__ in, size_t offOut, int R, int C) {
  u16* out = (u16*)(g_ws + offOut);
  __shared__ u16 t[64][68];  // row stride 136B: 8B-aligned, bounded bank aliasing
  int r0 = blockIdx.y * 64, c0 = blockIdx.x * 64;
  size_t mb = (size_t)blockIdx.z * R * C;
  in += mb; out += mb;
  int tid = threadIdx.x;
#pragma unroll
  for (int i = 0; i < 4; ++i) {
    int r = i * 16 + (tid >> 4);
    int c4 = (tid & 15) * 4;
    float4 v = *(const float4*)&in[(size_t)(r0 + r) * C + c0 + c4];
    u16x4 p;
    p[0] = f2h(v.x); p[1] = f2h(v.y); p[2] = f2h(v.z); p[3] = f2h(v.w);
    *(u16x4*)&t[r][c4] = p;
  }
  __syncthreads();
#pragma unroll
  for (int i = 0; i < 4; ++i) {
    int lin = i * 256 + tid;
    int cc = lin >> 4;            // 0..63 (out row)
    int rr0 = (lin & 15) * 4;     // 0..60 (out col block)
    u16x4 o;
    o[0] = t[rr0 + 0][cc];
    o[1] = t[rr0 + 1][cc];
    o[2] = t[rr0 + 2][cc];
    o[3] = t[rr0 + 3][cc];
    *(u16x4*)&out[(size_t)(c0 + cc) * R + r0 + rr0] = o;
  }
}

// ------- 256x256 MFMA GEMM: BK=64 double-buffered 2-phase (r17-proven structure) ----
// C[M][N](f16) = act(A[M][K] @ BT[N][K]^T + bias[N]); grouped via offs;
// INDIRECT: A row r read from token row tokmap[r] (ungrouped source).
// 512 threads = 8 waves (2M x 4N); BK=64; LDS 128KB (2 bufs x (A 32KB + B 32KB)).
// One vmcnt(0)+barrier per K-step: the ~1500cyc compute phase covers HBM latency.
// Swizzle: 16B slot' = slot ^ (row&7), applied on BOTH global-source chunk and
// LDS fragment read (within each 128B row -> staging coalescing preserved).
template <bool SILU, bool GROUPED, bool INDIRECT, int GN>
__global__ __launch_bounds__(512, 2) void gemm256(size_t offA, size_t offB,
                                                  const float* __restrict__ bias,
                                                  size_t offC, int Mfix, int N, int K) {
  const u16* A  = (const u16*)(g_ws + offA);
  const u16* BT = (const u16*)(g_ws + offB);
  u16* C = (u16*)(g_ws + offC);
  const int* offs = (const int*)(g_ws + OFF_MISC) + 8;
  const int* tokmap = (const int*)(g_ws + OFF_TMAP);

  // XCD-contiguous index (bijective; nwg % 8 == 0 for all our grids)
  int nx = gridDim.x, ny = gridDim.y;
  int nwg = nx * ny * gridDim.z;
  int flat = (blockIdx.z * ny + blockIdx.y) * nx + blockIdx.x;
  int cpx = nwg >> 3;
  int u = (flat & 7) * cpx + (flat >> 3);
  // decode u -> (bz, g, by, bxin): GN-wide bx supertile keeps B-group ~2MB L2-hot
  int bxin = u % GN;
  int t1 = u / GN;
  int by = t1 % ny;
  int t2 = t1 / ny;
  int nxg = nx / GN;
  int g = t2 % nxg;
  int bz = t2 / nxg;
  int bx = g * GN + bxin;

  int e = GROUPED ? bz : 0;
  int rbase = GROUPED ? offs[e] : 0;
  int Me = GROUPED ? (offs[e + 1] - rbase) : Mfix;
  int m0 = by * 256;
  if (m0 >= Me) return;
  int n0 = bx * 256;
  const u16* Be = BT + (size_t)e * N * K;
  const float* be = bias + (size_t)e * N;

  // LDS 128KB: A buf b at b*16384, B buf b at 32768 + b*16384 (u16 units).
  // Each buf = [256 rows][64 f16] (128B rows, 8x 16B slots). Epilogue reuses all as Cs.
  __shared__ __align__(128) u16 SM[65536];

  int tid = threadIdx.x;
  int lane = tid & 63, wid = tid >> 6;
  int wm = wid >> 2, wn = wid & 3;     // 2 x 4 wave grid
  int rsel = lane & 15;
  int rg = lane >> 4;                  // 0..3
  int sp0 = (rg ^ (rsel & 7)) * 8;     // swizzled slot base (k-slice 0); slice 1 = sp0 ^ 32

  // staging: q = i*512 + tid -> row = q>>3 (64 per i-step), chunk cnom = q&7;
  // global source chunk csrc = cnom ^ (row&7)  [row&7 == srow&7 for all i]
  int srow = tid >> 3;                 // 0..63
  int cnom = tid & 7;
  int csrc = (cnom ^ (srow & 7)) * 8;  // element offset within the row

  const u16* aP[4];
  const u16* bP[4];
#pragma unroll
  for (int i = 0; i < 4; ++i) {
    int r = m0 + i * 64 + srow;
    if (GROUPED) r = (r < Me) ? r : (Me - 1);
    if (INDIRECT) aP[i] = A + (size_t)tokmap[rbase + r] * K + csrc;
    else          aP[i] = A + (size_t)(rbase + r) * K + csrc;
    bP[i] = Be + (size_t)(n0 + i * 64 + srow) * K + csrc;
  }

#define STAGE(b, k0)                                                        \
  do {                                                                      \
    _Pragma("unroll") for (int i = 0; i < 4; ++i)                           \
      async_cp16(aP[i] + (k0), &SM[(b)*16384 + (i * 512 + tid) * 8]);       \
    _Pragma("unroll") for (int i = 0; i < 4; ++i)                           \
      async_cp16(bP[i] + (k0), &SM[32768 + (b)*16384 + (i * 512 + tid) * 8]); \
  } while (0)

#define COMPUTE(bb)                                                             \
  {                                                                             \
    const u16* Ab = &SM[(bb)*16384];                                            \
    const u16* Bb = &SM[32768 + (bb)*16384];                                    \
    _Pragma("unroll") for (int ks = 0; ks < 2; ++ks) {                          \
      int spo = sp0 ^ (ks << 5);                                                \
      f16x8 af[8], bf[4];                                                       \
      _Pragma("unroll") for (int i = 0; i < 8; ++i)                             \
        af[i] = *(const f16x8*)&Ab[wm * 8192 + i * 1024 + rsel * 64 + spo];     \
      _Pragma("unroll") for (int j = 0; j < 4; ++j)                             \
        bf[j] = *(const f16x8*)&Bb[wn * 4096 + j * 1024 + rsel * 64 + spo];     \
      _Pragma("unroll") for (int i = 0; i < 8; ++i)                             \
        _Pragma("unroll") for (int j = 0; j < 4; ++j)                           \
          acc[i][j] = __builtin_amdgcn_mfma_f32_16x16x32_f16(af[i], bf[j],      \
                                                             acc[i][j], 0, 0, 0); \
    }                                                                           \
  }

  f32x4 acc[8][4] = {};
  int nt = K >> 6;  // K-steps of 64

  STAGE(0, 0);
  asm volatile("s_waitcnt vmcnt(0)" ::: "memory");
  __builtin_amdgcn_s_barrier();

  int buf = 0;
  for (int t = 0; t < nt; ++t) {
    if (t + 1 < nt) STAGE(buf ^ 1, (t + 1) << 6);  // issue next tile FIRST
    COMPUTE(buf);
    asm volatile("s_waitcnt vmcnt(0)" ::: "memory");  // next tile landed
    __builtin_amdgcn_s_barrier();
    buf ^= 1;
  }
#undef COMPUTE
#undef STAGE

  // ---- epilogue: stage C-tile in LDS (reuse all 128KB = 256x256 f16), store coalesced ----
  u16* Cs = SM;
#pragma unroll
  for (int j = 0; j < 4; ++j) {
    int colL = wn * 64 + j * 16 + rsel;
    float bn = be[n0 + colL];
#pragma unroll
    for (int i = 0; i < 8; ++i) {
#pragma unroll
      for (int r = 0; r < 4; ++r) {
        int ml = wm * 128 + i * 16 + rg * 4 + r;
        float v = acc[i][j][r] + bn;
        if (SILU) v = v / (1.0f + __expf(-v));
        Cs[ml * 256 + colL] = f2h(v);
      }
    }
  }
  __syncthreads();
#pragma unroll
  for (int i = 0; i < 16; ++i) {
    int lin = i * 512 + tid;          // 8192 chunks of 16B
    int row = lin >> 5, sl = lin & 31;
    if (!GROUPED || (m0 + row < Me))
      *(uint4*)(C + (size_t)(rbase + m0 + row) * N + n0 + sl * 8) =
          *(const uint4*)&Cs[row * 256 + sl * 8];
  }
}

// ---------------- router logits + top2 + margin flagging ----------------
// rw2 consumed via RW2T [8][HIDD] f16: 16 vector loads/thread (was 128 scalar).
__global__ void k_router(const float* __restrict__ rb2, const float* __restrict__ x) {
  const u16* HR = (const u16*)(g_ws + OFF_HR);
  const u16* RW2T = (const u16*)(g_ws + OFF_RW2T);
  int* kidx = (int*)(g_ws + OFF_KIDX);
  float* kw = (float*)(g_ws + OFF_KW);
  int* flag = (int*)(g_ws + OFF_FLAG);
  float* XF = (float*)(g_ws + OFF_XF);
  int* misc = (int*)(g_ws + OFF_MISC);

  int t = blockIdx.x, tid = threadIdx.x;
  int lane = tid & 63, w = tid >> 6;
  float acc[8] = {};
  const u16* hrow = HR + (size_t)t * HIDD;
#pragma unroll
  for (int i = 0; i < 2; ++i) {
    int base = i * 2048 + tid * 8;
    f16x8 v = *(const f16x8*)&hrow[base];
    float hv[8];
#pragma unroll
    for (int jj = 0; jj < 8; ++jj) hv[jj] = (float)v[jj];
#pragma unroll
    for (int e2 = 0; e2 < 8; ++e2) {
      f16x8 wv = *(const f16x8*)&RW2T[e2 * HIDD + base];
#pragma unroll
      for (int jj = 0; jj < 8; ++jj) acc[e2] += hv[jj] * (float)wv[jj];
    }
  }
#pragma unroll
  for (int m = 1; m < 64; m <<= 1)
#pragma unroll
    for (int e2 = 0; e2 < 8; ++e2) acc[e2] += __shfl_xor(acc[e2], m);

  __shared__ float red[4][8];
  __shared__ int s_fi;
  if (lane == 0)
    for (int e2 = 0; e2 < 8; ++e2) red[w][e2] = acc[e2];
  if (tid == 0) s_fi = -1;
  __syncthreads();
  if (tid == 0) {
    float lg[8];
    for (int e2 = 0; e2 < 8; ++e2)
      lg[e2] = red[0][e2] + red[1][e2] + red[2][e2] + red[3][e2] + rb2[e2];
    int i1 = 0; float l1 = lg[0];
    for (int e2 = 1; e2 < 8; ++e2) if (lg[e2] > l1) { l1 = lg[e2]; i1 = e2; }
    int i2 = -1; float l2 = -3.4e38f;
    for (int e2 = 0; e2 < 8; ++e2) if (e2 != i1 && lg[e2] > l2) { l2 = lg[e2]; i2 = e2; }
    float l3 = -3.4e38f;
    for (int e2 = 0; e2 < 8; ++e2) if (e2 != i1 && e2 != i2 && lg[e2] > l3) l3 = lg[e2];
    float ex = __expf(l2 - l1);
    float inv = 1.0f / (1.0f + ex);
    kidx[2 * t] = i1; kidx[2 * t + 1] = i2;
    kw[2 * t] = inv;  kw[2 * t + 1] = ex * inv;
    if (l2 - l3 < 4e-3f) {  // near-tie: needs exact fp32 rescue
      int fi = atomicAdd(misc + 30, 1);
      if (fi < 512) { flag[fi] = t; s_fi = fi; }
    }
  }
  __syncthreads();
  int fi = s_fi;
  if (fi >= 0) {
    const float* xs = x + (size_t)t * EMBD;
    float* xd = XF + (size_t)fi * EMBD;
    int d = tid * 4;
    *(float4*)(xd + d) = *(const float4*)(xs + d);
  }
}

// exact fp32 router hidden for flagged tokens: HF = silu(XF @ rw1 + rb1)
__global__ __launch_bounds__(256) void k_flag_gemm(const float* __restrict__ rw1,
                                                   const float* __restrict__ rb1) {
  int* misc = (int*)(g_ws + OFF_MISC);
  int F = misc[30]; if (F > 512) F = 512;
  int m0 = blockIdx.y * 64;
  if (m0 >= F) return;
  int n0 = blockIdx.x * 64;
  const float* XF = (const float*)(g_ws + OFF_XF);
  float* HF = (float*)(g_ws + OFF_HF);
  __shared__ float As[64][17];
  __shared__ float Bs[16][65];
  int tid = threadIdx.x;
  float acc[4][4] = {};
  for (int k0 = 0; k0 < EMBD; k0 += 16) {
#pragma unroll
    for (int i = 0; i < 4; ++i) {
      int lin = i * 256 + tid;
      As[lin >> 4][lin & 15] = XF[(size_t)(m0 + (lin >> 4)) * EMBD + k0 + (lin & 15)];
      Bs[lin >> 6][lin & 63] = rw1[(size_t)(k0 + (lin >> 6)) * HIDD + n0 + (lin & 63)];
    }
    __syncthreads();
    int ty = tid >> 4, tx = tid & 15;
#pragma unroll
    for (int kk = 0; kk < 16; ++kk) {
      float a4[4], b4[4];
#pragma unroll
      for (int a = 0; a < 4; ++a) a4[a] = As[ty * 4 + a][kk];
#pragma unroll
      for (int b = 0; b < 4; ++b) b4[b] = Bs[kk][tx * 4 + b];
#pragma unroll
      for (int a = 0; a < 4; ++a)
#pragma unroll
        for (int b = 0; b < 4; ++b) acc[a][b] += a4[a] * b4[b];
    }
    __syncthreads();
  }
  int ty = tid >> 4, tx = tid & 15;
  for (int a = 0; a < 4; ++a)
    for (int b = 0; b < 4; ++b) {
      int n = n0 + tx * 4 + b;
      float v = acc[a][b] + rb1[n];
      v = v / (1.0f + __expf(-v));
      HF[(size_t)(m0 + ty * 4 + a) * HIDD + n] = v;
    }
}

__global__ void k_flag_fix(const float* __restrict__ rw2, const float* __restrict__ rb2) {
  int* misc = (int*)(g_ws + OFF_MISC);
  int F = misc[30]; if (F > 512) F = 512;
  int fi = blockIdx.x; if (fi >= F) return;
  const int* flag = (const int*)(g_ws + OFF_FLAG);
  const float* HF = (const float*)(g_ws + OFF_HF);
  int* kidx = (int*)(g_ws + OFF_KIDX);
  float* kw = (float*)(g_ws + OFF_KW);
  int t = flag[fi];
  int tid = threadIdx.x, lane = tid & 63, w = tid >> 6;
  const float* h = HF + (size_t)fi * HIDD;
  float acc[8] = {};
  for (int i = 0; i < 16; ++i) {
    int hh = i * 256 + tid;
    float hv = h[hh];
    const float* r2 = rw2 + (size_t)hh * 8;
#pragma unroll
    for (int e2 = 0; e2 < 8; ++e2) acc[e2] += hv * r2[e2];
  }
#pragma unroll
  for (int m = 1; m < 64; m <<= 1)
#pragma unroll
    for (int e2 = 0; e2 < 8; ++e2) acc[e2] += __shfl_xor(acc[e2], m);
  __shared__ float red[4][8];
  if (lane == 0)
    for (int e2 = 0; e2 < 8; ++e2) red[w][e2] = acc[e2];
  __syncthreads();
  if (tid == 0) {
    float lg[8];
    for (int e2 = 0; e2 < 8; ++e2)
      lg[e2] = red[0][e2] + red[1][e2] + red[2][e2] + red[3][e2] + rb2[e2];
    int i1 = 0; float l1 = lg[0];
    for (int e2 = 1; e2 < 8; ++e2) if (lg[e2] > l1) { l1 = lg[e2]; i1 = e2; }
    int i2 = -1; float l2 = -3.4e38f;
    for (int e2 = 0; e2 < 8; ++e2) if (e2 != i1 && lg[e2] > l2) { l2 = lg[e2]; i2 = e2; }
    float ex = __expf(l2 - l1);
    float inv = 1.0f / (1.0f + ex);
    kidx[2 * t] = i1; kidx[2 * t + 1] = i2;
    kw[2 * t] = inv;  kw[2 * t + 1] = ex * inv;
  }
}

// fused count + scan: single block, register histograms + wave reduce + scan
__global__ __launch_bounds__(1024) void k_count_scan() {
  const int* kidx = (const int*)(g_ws + OFF_KIDX);
  int* misc = (int*)(g_ws + OFF_MISC);
  int tid = threadIdx.x;
  int c[8] = {};
  for (int i = tid; i < 2 * TOK; i += 1024) {
    int e = kidx[i];
#pragma unroll
    for (int k = 0; k < 8; ++k) c[k] += (e == k) ? 1 : 0;
  }
#pragma unroll
  for (int m = 1; m < 64; m <<= 1)
#pragma unroll
    for (int k = 0; k < 8; ++k) c[k] += __shfl_xor(c[k], m);
  __shared__ int red[16][8];
  int lane = tid & 63, w = tid >> 6;
  if (lane == 0)
#pragma unroll
    for (int k = 0; k < 8; ++k) red[w][k] = c[k];
  __syncthreads();
  if (tid == 0) {
    int* offs = misc + 8;
    int* cur = misc + 20;
    offs[0] = 0;
    for (int e = 0; e < 8; ++e) {
      int s = 0;
      for (int ww = 0; ww < 16; ++ww) s += red[ww][e];
      offs[e + 1] = offs[e] + s;
      cur[e] = offs[e];
    }
  }
}

// map-only: slot s -> grouped row r (rowmap), grouped row r -> token (tokmap)
__global__ void k_build() {
  int s = blockIdx.x * 256 + threadIdx.x;
  if (s < 2 * TOK) {
    const int* kidx = (const int*)(g_ws + OFF_KIDX);
    int* rowmap = (int*)(g_ws + OFF_RMAP);
    int* tokmap = (int*)(g_ws + OFF_TMAP);
    int* misc = (int*)(g_ws + OFF_MISC);
    int e = kidx[s];
    int r = atomicAdd(&misc[20 + e], 1);
    rowmap[s] = r;
    tokmap[r] = s >> 1;
  }
}

__global__ void k_combine(float* __restrict__ out) {
  int t = blockIdx.x, tid = threadIdx.x;
  const int* rowmap = (const int*)(g_ws + OFF_RMAP);
  const float* kw = (const float*)(g_ws + OFF_KW);
  const u16* YG = (const u16*)(g_ws + OFF_YG);
  int r0 = rowmap[2 * t], r1 = rowmap[2 * t + 1];
  float w0 = kw[2 * t], w1 = kw[2 * t + 1];
  int d = tid * 4;
  f16x4 a = *(const f16x4*)(YG + (size_t)r0 * EMBD + d);
  f16x4 b = *(const f16x4*)(YG + (size_t)r1 * EMBD + d);
  float4 o;
  o.x = w0 * (float)a[0] + w1 * (float)b[0];
  o.y = w0 * (float)a[1] + w1 * (float)b[1];
  o.z = w0 * (float)a[2] + w1 * (float)b[2];
  o.w = w0 * (float)a[3] + w1 * (float)b[3];
  *(float4*)(out + (size_t)t * EMBD + d) = o;
}

// ---------------- launch ----------------
extern "C" void kernel_launch(void* const* d_in, const int* in_sizes, int n_in,
                              void* d_out, int out_size, void* d_ws, size_t ws_size,
                              hipStream_t stream) {
  const float* x   = (const float*)d_in[0];
  const float* rw1 = (const float*)d_in[1];
  const float* rb1 = (const float*)d_in[2];
  const float* rw2 = (const float*)d_in[3];
  const float* rb2 = (const float*)d_in[4];
  const float* w1  = (const float*)d_in[5];
  const float* b1  = (const float*)d_in[6];
  const float* w2  = (const float*)d_in[7];
  const float* b2  = (const float*)d_in[8];
  float* out = (float*)d_out;

  k_prep<<<dim3(TOK * EMBD / 1024 + HIDD / 256 + 1), dim3(256), 0, stream>>>(x, rw2);
  k_transpose<<<dim3(HIDD / 64, EMBD / 64, 1), dim3(256), 0, stream>>>(rw1, OFF_RW1T, EMBD, HIDD);
  k_transpose<<<dim3(HIDD / 64, EMBD / 64, 8), dim3(256), 0, stream>>>(w1, OFF_W1T, EMBD, HIDD);
  k_transpose<<<dim3(EMBD / 64, HIDD / 64, 8), dim3(256), 0, stream>>>(w2, OFF_W2T, HIDD, EMBD);
  // router GEMM1: [8192 x 4096 x 1024], GN=4 (2MB B-group at K=1024)
  gemm256<true, false, false, 4><<<dim3(HIDD / 256, TOK / 256, 1), dim3(512), 0, stream>>>(
      OFF_X16, OFF_RW1T, rb1, OFF_HR, TOK, HIDD, EMBD);
  k_router<<<dim3(TOK), dim3(256), 0, stream>>>(rb2, x);
  k_flag_gemm<<<dim3(HIDD / 64, 8), dim3(256), 0, stream>>>(rw1, rb1);
  k_flag_fix<<<dim3(512), dim3(256), 0, stream>>>(rw2, rb2);
  k_count_scan<<<dim3(1), dim3(1024), 0, stream>>>();
  k_build<<<dim3(2 * TOK / 256), dim3(256), 0, stream>>>();
  // expert GEMM1: grouped [~16384 x 4096 x 1024], A gathered via tokmap, GN=4
  gemm256<true, true, true, 4><<<dim3(HIDD / 256, 2 * TOK / 256, 8), dim3(512), 0, stream>>>(
      OFF_X16, OFF_W1T, b1, OFF_HG, 0, HIDD, EMBD);
  // expert GEMM2: grouped [~16384 x 1024 x 4096], GN=1 (B-panel 2MB at K=4096)
  gemm256<false, true, false, 1><<<dim3(EMBD / 256, 2 * TOK / 256, 8), dim3(512), 0, stream>>>(
      OFF_HG, OFF_W2T, b2, OFF_YG, 0, EMBD, HIDD);
  k_combine<<<dim3(TOK), dim3(256), 0, stream>>>(out);
}

// Round 22
// 810.602 us; speedup vs baseline: 1.2119x; 1.0126x over previous
//
#include <hip/hip_runtime.h>
#include <stdint.h>

#define TOK 8192
#define EMBD 1024
#define HIDD 4096
#define NEXP 8

typedef _Float16 f16;
typedef _Float16 f16x8 __attribute__((ext_vector_type(8)));
typedef _Float16 f16x4 __attribute__((ext_vector_type(4)));
typedef float f32x4 __attribute__((ext_vector_type(4)));
typedef unsigned short u16;
typedef unsigned short u16x4 __attribute__((ext_vector_type(4)));

// ---------------- static workspace arena ----------------
constexpr size_t OFF_X16   = 0;                                      // [TOK][EMBD] f16
constexpr size_t OFF_RW1T  = OFF_X16  + (size_t)TOK*EMBD*2;          // [HIDD][EMBD] f16
constexpr size_t OFF_W1T   = OFF_RW1T + (size_t)HIDD*EMBD*2;         // [E][HIDD][EMBD] f16
constexpr size_t OFF_W2T   = OFF_W1T  + (size_t)NEXP*HIDD*EMBD*2;    // [E][EMBD][HIDD] f16
constexpr size_t OFF_HR    = OFF_W2T  + (size_t)NEXP*EMBD*HIDD*2;    // [TOK][HIDD] f16
constexpr size_t OFF_HG    = OFF_HR   + (size_t)TOK*HIDD*2;          // [2T+256][HIDD] f16
constexpr size_t OFF_YG    = OFF_HG   + (size_t)(2*TOK+256)*HIDD*2;  // [2T+256][EMBD] f16
constexpr size_t OFF_XF    = OFF_YG   + (size_t)(2*TOK+256)*EMBD*2;  // [512][EMBD] f32
constexpr size_t OFF_HF    = OFF_XF   + 512UL*EMBD*4;                // [512][HIDD] f32
constexpr size_t OFF_KIDX  = OFF_HF   + 512UL*HIDD*4;                // [2T] int
constexpr size_t OFF_KW    = OFF_KIDX + 2UL*TOK*4;                   // [2T] f32
constexpr size_t OFF_RMAP  = OFF_KW   + 2UL*TOK*4;                   // [2T] int (token-slot -> grouped row)
constexpr size_t OFF_TMAP  = OFF_RMAP + 2UL*TOK*4;                   // [2T] int (grouped row -> token)
constexpr size_t OFF_FLAG  = OFF_TMAP + 2UL*TOK*4;                   // [512] int
constexpr size_t OFF_MISC  = OFF_FLAG + 512UL*4;                     // counts[8],offs[9]@8,cur[8]@20,nf@30
constexpr size_t OFF_RW2T  = OFF_MISC + 1024;                        // [8][HIDD] f16
constexpr size_t WS_TOTAL  = OFF_RW2T + (size_t)NEXP*HIDD*2;

__device__ __align__(1024) unsigned char g_ws[WS_TOTAL];

__device__ __forceinline__ u16 f2h(float f) {
  f16 h = (f16)f;
  return __builtin_bit_cast(u16, h);
}

__device__ __forceinline__ void async_cp16(const void* g, void* l) {
  __builtin_amdgcn_global_load_lds((const __attribute__((address_space(1))) void*)g,
                                   (__attribute__((address_space(3))) void*)l, 16, 0, 0);
}

// ---------------- fused prep: x->f16, rw2 transpose->f16, misc init ----------------
// blocks [0, TOK*EMBD/1024): cvt x; next HIDD/256 blocks: cvt rw2; last block: init.
__global__ void k_prep(const float* __restrict__ x, const float* __restrict__ rw2) {
  int b = blockIdx.x, tid = threadIdx.x;
  constexpr int NBX = TOK * EMBD / 1024;
  if (b < NBX) {
    u16* X16 = (u16*)(g_ws + OFF_X16);
    int i = (b * 256 + tid) * 4;
    float4 v = *(const float4*)(x + i);
    u16x4 o;
    o[0] = f2h(v.x); o[1] = f2h(v.y); o[2] = f2h(v.z); o[3] = f2h(v.w);
    *(u16x4*)(X16 + i) = o;
  } else if (b < NBX + HIDD / 256) {
    u16* RW2T = (u16*)(g_ws + OFF_RW2T);
    int h = (b - NBX) * 256 + tid;  // 0..4095
    float4 a = *(const float4*)&rw2[(size_t)h * 8];
    float4 bb = *(const float4*)&rw2[(size_t)h * 8 + 4];
    RW2T[0 * HIDD + h] = f2h(a.x);
    RW2T[1 * HIDD + h] = f2h(a.y);
    RW2T[2 * HIDD + h] = f2h(a.z);
    RW2T[3 * HIDD + h] = f2h(a.w);
    RW2T[4 * HIDD + h] = f2h(bb.x);
    RW2T[5 * HIDD + h] = f2h(bb.y);
    RW2T[6 * HIDD + h] = f2h(bb.z);
    RW2T[7 * HIDD + h] = f2h(bb.w);
  } else {
    if (tid < 32) ((int*)(g_ws + OFF_MISC))[tid] = 0;
  }
}

// ---- fused weight transposes: fp32 [R][C] -> f16 [C][R], XOR-swizzled LDS ----
// Pass 1 stores slot c4 ^ ((r>>2 & 15)<<2); pass 2 reads with the same XOR
// ((rr0+k)>>2 == lin&15 for k=0..3). Read banks 10L%32 (16 distinct) -> no
// conflicts; store = 16 distinct 8B slots per row -> no conflicts.
template <int R, int C>
__device__ __forceinline__ void tpose(const float* __restrict__ src, u16* __restrict__ dst,
                                      int bx, int by, u16 (*t)[68]) {
  int r0 = by * 64, c0 = bx * 64;
  int tid = threadIdx.x;
#pragma unroll
  for (int i = 0; i < 4; ++i) {
    int r = i * 16 + (tid >> 4);
    int c4 = (tid & 15) * 4;
    float4 v = *(const float4*)&src[(size_t)(r0 + r) * C + c0 + c4];
    u16x4 p;
    p[0] = f2h(v.x); p[1] = f2h(v.y); p[2] = f2h(v.z); p[3] = f2h(v.w);
    *(u16x4*)&t[r][c4 ^ (((r >> 2) & 15) << 2)] = p;
  }
  __syncthreads();
#pragma unroll
  for (int i = 0; i < 4; ++i) {
    int lin = i * 256 + tid;
    int cc = lin >> 4;            // 0..63 (out row)
    int q = lin & 15;
    int rr0 = q * 4;              // 0..60 (out col block)
    int cs = cc ^ (q << 2);       // swizzled source column
    u16x4 o;
    o[0] = t[rr0 + 0][cs];
    o[1] = t[rr0 + 1][cs];
    o[2] = t[rr0 + 2][cs];
    o[3] = t[rr0 + 3][cs];
    *(u16x4*)&dst[(size_t)(c0 + cc) * R + r0 + rr0] = o;
  }
}

// blocks [0, 9216): rw1 (m=0) + w1 (m=1..8), R=EMBD,C=HIDD (RW1T/W1T contiguous);
// blocks [9216, 17408): w2 (8 matrices), R=HIDD,C=EMBD.
__global__ void k_transpose_all(const float* __restrict__ rw1, const float* __restrict__ w1,
                                const float* __restrict__ w2) {
  __shared__ u16 t[64][68];
  int flat = blockIdx.x;
  if (flat < 9 * 1024) {
    int m = flat >> 10, rem = flat & 1023;
    int bx = rem & 63, by = rem >> 6;   // C/64 = 64, R/64 = 16
    const float* src = (m == 0) ? rw1 : w1 + (size_t)(m - 1) * EMBD * HIDD;
    u16* dst = (u16*)(g_ws + OFF_RW1T) + (size_t)m * HIDD * EMBD;
    tpose<EMBD, HIDD>(src, dst, bx, by, t);
  } else {
    int f2 = flat - 9 * 1024;
    int m = f2 >> 10, rem = f2 & 1023;
    int bx = rem & 15, by = rem >> 4;   // C/64 = 16, R/64 = 64
    const float* src = w2 + (size_t)m * HIDD * EMBD;
    u16* dst = (u16*)(g_ws + OFF_W2T) + (size_t)m * EMBD * HIDD;
    tpose<HIDD, EMBD>(src, dst, bx, by, t);
  }
}

// ------- 256x256 MFMA GEMM: BK=64 double-buffered 2-phase (r17-proven structure) ----
// C[M][N](f16) = act(A[M][K] @ BT[N][K]^T + bias[N]); grouped via offs;
// INDIRECT: A row r read from token row tokmap[r] (ungrouped source).
// 512 threads = 8 waves (2M x 4N); BK=64; LDS 128KB (2 bufs x (A 32KB + B 32KB)).
// One vmcnt(0)+barrier per K-step: the ~1500cyc compute phase covers HBM latency.
// Swizzle: 16B slot' = slot ^ (row&7), applied on BOTH global-source chunk and
// LDS fragment read (within each 128B row -> staging coalescing preserved).
template <bool SILU, bool GROUPED, bool INDIRECT, int GN>
__global__ __launch_bounds__(512, 2) void gemm256(size_t offA, size_t offB,
                                                  const float* __restrict__ bias,
                                                  size_t offC, int Mfix, int N, int K) {
  const u16* A  = (const u16*)(g_ws + offA);
  const u16* BT = (const u16*)(g_ws + offB);
  u16* C = (u16*)(g_ws + offC);
  const int* offs = (const int*)(g_ws + OFF_MISC) + 8;
  const int* tokmap = (const int*)(g_ws + OFF_TMAP);

  // XCD-contiguous index (bijective; nwg % 8 == 0 for all our grids)
  int nx = gridDim.x, ny = gridDim.y;
  int nwg = nx * ny * gridDim.z;
  int flat = (blockIdx.z * ny + blockIdx.y) * nx + blockIdx.x;
  int cpx = nwg >> 3;
  int u = (flat & 7) * cpx + (flat >> 3);
  // decode u -> (bz, g, by, bxin): GN-wide bx supertile keeps B-group ~2MB L2-hot
  int bxin = u % GN;
  int t1 = u / GN;
  int by = t1 % ny;
  int t2 = t1 / ny;
  int nxg = nx / GN;
  int g = t2 % nxg;
  int bz = t2 / nxg;
  int bx = g * GN + bxin;

  int e = GROUPED ? bz : 0;
  int rbase = GROUPED ? offs[e] : 0;
  int Me = GROUPED ? (offs[e + 1] - rbase) : Mfix;
  int m0 = by * 256;
  if (m0 >= Me) return;
  int n0 = bx * 256;
  const u16* Be = BT + (size_t)e * N * K;
  const float* be = bias + (size_t)e * N;

  // LDS 128KB: A buf b at b*16384, B buf b at 32768 + b*16384 (u16 units).
  // Each buf = [256 rows][64 f16] (128B rows, 8x 16B slots). Epilogue reuses all as Cs.
  __shared__ __align__(128) u16 SM[65536];

  int tid = threadIdx.x;
  int lane = tid & 63, wid = tid >> 6;
  int wm = wid >> 2, wn = wid & 3;     // 2 x 4 wave grid
  int rsel = lane & 15;
  int rg = lane >> 4;                  // 0..3
  int sp0 = (rg ^ (rsel & 7)) * 8;     // swizzled slot base (k-slice 0); slice 1 = sp0 ^ 32

  // staging: q = i*512 + tid -> row = q>>3 (64 per i-step), chunk cnom = q&7;
  // global source chunk csrc = cnom ^ (row&7)  [row&7 == srow&7 for all i]
  int srow = tid >> 3;                 // 0..63
  int cnom = tid & 7;
  int csrc = (cnom ^ (srow & 7)) * 8;  // element offset within the row

  const u16* aP[4];
  const u16* bP[4];
#pragma unroll
  for (int i = 0; i < 4; ++i) {
    int r = m0 + i * 64 + srow;
    if (GROUPED) r = (r < Me) ? r : (Me - 1);
    if (INDIRECT) aP[i] = A + (size_t)tokmap[rbase + r] * K + csrc;
    else          aP[i] = A + (size_t)(rbase + r) * K + csrc;
    bP[i] = Be + (size_t)(n0 + i * 64 + srow) * K + csrc;
  }

#define STAGE(b, k0)                                                        \
  do {                                                                      \
    _Pragma("unroll") for (int i = 0; i < 4; ++i)                           \
      async_cp16(aP[i] + (k0), &SM[(b)*16384 + (i * 512 + tid) * 8]);       \
    _Pragma("unroll") for (int i = 0; i < 4; ++i)                           \
      async_cp16(bP[i] + (k0), &SM[32768 + (b)*16384 + (i * 512 + tid) * 8]); \
  } while (0)

#define COMPUTE(bb)                                                             \
  {                                                                             \
    const u16* Ab = &SM[(bb)*16384];                                            \
    const u16* Bb = &SM[32768 + (bb)*16384];                                    \
    _Pragma("unroll") for (int ks = 0; ks < 2; ++ks) {                          \
      int spo = sp0 ^ (ks << 5);                                                \
      f16x8 af[8], bf[4];                                                       \
      _Pragma("unroll") for (int i = 0; i < 8; ++i)                             \
        af[i] = *(const f16x8*)&Ab[wm * 8192 + i * 1024 + rsel * 64 + spo];     \
      _Pragma("unroll") for (int j = 0; j < 4; ++j)                             \
        bf[j] = *(const f16x8*)&Bb[wn * 4096 + j * 1024 + rsel * 64 + spo];     \
      _Pragma("unroll") for (int i = 0; i < 8; ++i)                             \
        _Pragma("unroll") for (int j = 0; j < 4; ++j)                           \
          acc[i][j] = __builtin_amdgcn_mfma_f32_16x16x32_f16(af[i], bf[j],      \
                                                             acc[i][j], 0, 0, 0); \
    }                                                                           \
  }

  f32x4 acc[8][4] = {};
  int nt = K >> 6;  // K-steps of 64

  STAGE(0, 0);
  asm volatile("s_waitcnt vmcnt(0)" ::: "memory");
  __builtin_amdgcn_s_barrier();

  int buf = 0;
  for (int t = 0; t < nt; ++t) {
    if (t + 1 < nt) STAGE(buf ^ 1, (t + 1) << 6);  // issue next tile FIRST
    COMPUTE(buf);
    asm volatile("s_waitcnt vmcnt(0)" ::: "memory");  // next tile landed
    __builtin_amdgcn_s_barrier();
    buf ^= 1;
  }
#undef COMPUTE
#undef STAGE

  // ---- epilogue: stage C-tile in LDS (reuse all 128KB = 256x256 f16), store coalesced ----
  u16* Cs = SM;
#pragma unroll
  for (int j = 0; j < 4; ++j) {
    int colL = wn * 64 + j * 16 + rsel;
    float bn = be[n0 + colL];
#pragma unroll
    for (int i = 0; i < 8; ++i) {
#pragma unroll
      for (int r = 0; r < 4; ++r) {
        int ml = wm * 128 + i * 16 + rg * 4 + r;
        float v = acc[i][j][r] + bn;
        if (SILU) v = v / (1.0f + __expf(-v));
        Cs[ml * 256 + colL] = f2h(v);
      }
    }
  }
  __syncthreads();
#pragma unroll
  for (int i = 0; i < 16; ++i) {
    int lin = i * 512 + tid;          // 8192 chunks of 16B
    int row = lin >> 5, sl = lin & 31;
    if (!GROUPED || (m0 + row < Me))
      *(uint4*)(C + (size_t)(rbase + m0 + row) * N + n0 + sl * 8) =
          *(const uint4*)&Cs[row * 256 + sl * 8];
  }
}

// ---------------- router logits + top2 + margin flagging ----------------
// rw2 consumed via RW2T [8][HIDD] f16: 16 vector loads/thread (was 128 scalar).
__global__ void k_router(const float* __restrict__ rb2, const float* __restrict__ x) {
  const u16* HR = (const u16*)(g_ws + OFF_HR);
  const u16* RW2T = (const u16*)(g_ws + OFF_RW2T);
  int* kidx = (int*)(g_ws + OFF_KIDX);
  float* kw = (float*)(g_ws + OFF_KW);
  int* flag = (int*)(g_ws + OFF_FLAG);
  float* XF = (float*)(g_ws + OFF_XF);
  int* misc = (int*)(g_ws + OFF_MISC);

  int t = blockIdx.x, tid = threadIdx.x;
  int lane = tid & 63, w = tid >> 6;
  float acc[8] = {};
  const u16* hrow = HR + (size_t)t * HIDD;
#pragma unroll
  for (int i = 0; i < 2; ++i) {
    int base = i * 2048 + tid * 8;
    f16x8 v = *(const f16x8*)&hrow[base];
    float hv[8];
#pragma unroll
    for (int jj = 0; jj < 8; ++jj) hv[jj] = (float)v[jj];
#pragma unroll
    for (int e2 = 0; e2 < 8; ++e2) {
      f16x8 wv = *(const f16x8*)&RW2T[e2 * HIDD + base];
#pragma unroll
      for (int jj = 0; jj < 8; ++jj) acc[e2] += hv[jj] * (float)wv[jj];
    }
  }
#pragma unroll
  for (int m = 1; m < 64; m <<= 1)
#pragma unroll
    for (int e2 = 0; e2 < 8; ++e2) acc[e2] += __shfl_xor(acc[e2], m);

  __shared__ float red[4][8];
  __shared__ int s_fi;
  if (lane == 0)
    for (int e2 = 0; e2 < 8; ++e2) red[w][e2] = acc[e2];
  if (tid == 0) s_fi = -1;
  __syncthreads();
  if (tid == 0) {
    float lg[8];
    for (int e2 = 0; e2 < 8; ++e2)
      lg[e2] = red[0][e2] + red[1][e2] + red[2][e2] + red[3][e2] + rb2[e2];
    int i1 = 0; float l1 = lg[0];
    for (int e2 = 1; e2 < 8; ++e2) if (lg[e2] > l1) { l1 = lg[e2]; i1 = e2; }
    int i2 = -1; float l2 = -3.4e38f;
    for (int e2 = 0; e2 < 8; ++e2) if (e2 != i1 && lg[e2] > l2) { l2 = lg[e2]; i2 = e2; }
    float l3 = -3.4e38f;
    for (int e2 = 0; e2 < 8; ++e2) if (e2 != i1 && e2 != i2 && lg[e2] > l3) l3 = lg[e2];
    float ex = __expf(l2 - l1);
    float inv = 1.0f / (1.0f + ex);
    kidx[2 * t] = i1; kidx[2 * t + 1] = i2;
    kw[2 * t] = inv;  kw[2 * t + 1] = ex * inv;
    if (l2 - l3 < 4e-3f) {  // near-tie: needs exact fp32 rescue
      int fi = atomicAdd(misc + 30, 1);
      if (fi < 512) { flag[fi] = t; s_fi = fi; }
    }
  }
  __syncthreads();
  int fi = s_fi;
  if (fi >= 0) {
    const float* xs = x + (size_t)t * EMBD;
    float* xd = XF + (size_t)fi * EMBD;
    int d = tid * 4;
    *(float4*)(xd + d) = *(const float4*)(xs + d);
  }
}

// exact fp32 router hidden for flagged tokens: HF = silu(XF @ rw1 + rb1)
__global__ __launch_bounds__(256) void k_flag_gemm(const float* __restrict__ rw1,
                                                   const float* __restrict__ rb1) {
  int* misc = (int*)(g_ws + OFF_MISC);
  int F = misc[30]; if (F > 512) F = 512;
  int m0 = blockIdx.y * 64;
  if (m0 >= F) return;
  int n0 = blockIdx.x * 64;
  const float* XF = (const float*)(g_ws + OFF_XF);
  float* HF = (float*)(g_ws + OFF_HF);
  __shared__ float As[64][17];
  __shared__ float Bs[16][65];
  int tid = threadIdx.x;
  float acc[4][4] = {};
  for (int k0 = 0; k0 < EMBD; k0 += 16) {
#pragma unroll
    for (int i = 0; i < 4; ++i) {
      int lin = i * 256 + tid;
      As[lin >> 4][lin & 15] = XF[(size_t)(m0 + (lin >> 4)) * EMBD + k0 + (lin & 15)];
      Bs[lin >> 6][lin & 63] = rw1[(size_t)(k0 + (lin >> 6)) * HIDD + n0 + (lin & 63)];
    }
    __syncthreads();
    int ty = tid >> 4, tx = tid & 15;
#pragma unroll
    for (int kk = 0; kk < 16; ++kk) {
      float a4[4], b4[4];
#pragma unroll
      for (int a = 0; a < 4; ++a) a4[a] = As[ty * 4 + a][kk];
#pragma unroll
      for (int b = 0; b < 4; ++b) b4[b] = Bs[kk][tx * 4 + b];
#pragma unroll
      for (int a = 0; a < 4; ++a)
#pragma unroll
        for (int b = 0; b < 4; ++b) acc[a][b] += a4[a] * b4[b];
    }
    __syncthreads();
  }
  int ty = tid >> 4, tx = tid & 15;
  for (int a = 0; a < 4; ++a)
    for (int b = 0; b < 4; ++b) {
      int n = n0 + tx * 4 + b;
      float v = acc[a][b] + rb1[n];
      v = v / (1.0f + __expf(-v));
      HF[(size_t)(m0 + ty * 4 + a) * HIDD + n] = v;
    }
}

__global__ void k_flag_fix(const float* __restrict__ rw2, const float* __restrict__ rb2) {
  int* misc = (int*)(g_ws + OFF_MISC);
  int F = misc[30]; if (F > 512) F = 512;
  int fi = blockIdx.x; if (fi >= F) return;
  const int* flag = (const int*)(g_ws + OFF_FLAG);
  const float* HF = (const float*)(g_ws + OFF_HF);
  int* kidx = (int*)(g_ws + OFF_KIDX);
  float* kw = (float*)(g_ws + OFF_KW);
  int t = flag[fi];
  int tid = threadIdx.x, lane = tid & 63, w = tid >> 6;
  const float* h = HF + (size_t)fi * HIDD;
  float acc[8] = {};
  for (int i = 0; i < 16; ++i) {
    int hh = i * 256 + tid;
    float hv = h[hh];
    const float* r2 = rw2 + (size_t)hh * 8;
#pragma unroll
    for (int e2 = 0; e2 < 8; ++e2) acc[e2] += hv * r2[e2];
  }
#pragma unroll
  for (int m = 1; m < 64; m <<= 1)
#pragma unroll
    for (int e2 = 0; e2 < 8; ++e2) acc[e2] += __shfl_xor(acc[e2], m);
  __shared__ float red[4][8];
  if (lane == 0)
    for (int e2 = 0; e2 < 8; ++e2) red[w][e2] = acc[e2];
  __syncthreads();
  if (tid == 0) {
    float lg[8];
    for (int e2 = 0; e2 < 8; ++e2)
      lg[e2] = red[0][e2] + red[1][e2] + red[2][e2] + red[3][e2] + rb2[e2];
    int i1 = 0; float l1 = lg[0];
    for (int e2 = 1; e2 < 8; ++e2) if (lg[e2] > l1) { l1 = lg[e2]; i1 = e2; }
    int i2 = -1; float l2 = -3.4e38f;
    for (int e2 = 0; e2 < 8; ++e2) if (e2 != i1 && lg[e2] > l2) { l2 = lg[e2]; i2 = e2; }
    float ex = __expf(l2 - l1);
    float inv = 1.0f / (1.0f + ex);
    kidx[2 * t] = i1; kidx[2 * t + 1] = i2;
    kw[2 * t] = inv;  kw[2 * t + 1] = ex * inv;
  }
}

// fused count + scan: single block, register histograms + wave reduce + scan
__global__ __launch_bounds__(1024) void k_count_scan() {
  const int* kidx = (const int*)(g_ws + OFF_KIDX);
  int* misc = (int*)(g_ws + OFF_MISC);
  int tid = threadIdx.x;
  int c[8] = {};
  for (int i = tid; i < 2 * TOK; i += 1024) {
    int e = kidx[i];
#pragma unroll
    for (int k = 0; k < 8; ++k) c[k] += (e == k) ? 1 : 0;
  }
#pragma unroll
  for (int m = 1; m < 64; m <<= 1)
#pragma unroll
    for (int k = 0; k < 8; ++k) c[k] += __shfl_xor(c[k], m);
  __shared__ int red[16][8];
  int lane = tid & 63, w = tid >> 6;
  if (lane == 0)
#pragma unroll
    for (int k = 0; k < 8; ++k) red[w][k] = c[k];
  __syncthreads();
  if (tid == 0) {
    int* offs = misc + 8;
    int* cur = misc + 20;
    offs[0] = 0;
    for (int e = 0; e < 8; ++e) {
      int s = 0;
      for (int ww = 0; ww < 16; ++ww) s += red[ww][e];
      offs[e + 1] = offs[e] + s;
      cur[e] = offs[e];
    }
  }
}

// map-only: slot s -> grouped row r (rowmap), grouped row r -> token (tokmap)
__global__ void k_build() {
  int s = blockIdx.x * 256 + threadIdx.x;
  if (s < 2 * TOK) {
    const int* kidx = (const int*)(g_ws + OFF_KIDX);
    int* rowmap = (int*)(g_ws + OFF_RMAP);
    int* tokmap = (int*)(g_ws + OFF_TMAP);
    int* misc = (int*)(g_ws + OFF_MISC);
    int e = kidx[s];
    int r = atomicAdd(&misc[20 + e], 1);
    rowmap[s] = r;
    tokmap[r] = s >> 1;
  }
}

__global__ void k_combine(float* __restrict__ out) {
  int t = blockIdx.x, tid = threadIdx.x;
  const int* rowmap = (const int*)(g_ws + OFF_RMAP);
  const float* kw = (const float*)(g_ws + OFF_KW);
  const u16* YG = (const u16*)(g_ws + OFF_YG);
  int r0 = rowmap[2 * t], r1 = rowmap[2 * t + 1];
  float w0 = kw[2 * t], w1 = kw[2 * t + 1];
  int d = tid * 4;
  f16x4 a = *(const f16x4*)(YG + (size_t)r0 * EMBD + d);
  f16x4 b = *(const f16x4*)(YG + (size_t)r1 * EMBD + d);
  float4 o;
  o.x = w0 * (float)a[0] + w1 * (float)b[0];
  o.y = w0 * (float)a[1] + w1 * (float)b[1];
  o.z = w0 * (float)a[2] + w1 * (float)b[2];
  o.w = w0 * (float)a[3] + w1 * (float)b[3];
  *(float4*)(out + (size_t)t * EMBD + d) = o;
}

// ---------------- launch ----------------
extern "C" void kernel_launch(void* const* d_in, const int* in_sizes, int n_in,
                              void* d_out, int out_size, void* d_ws, size_t ws_size,
                              hipStream_t stream) {
  const float* x   = (const float*)d_in[0];
  const float* rw1 = (const float*)d_in[1];
  const float* rb1 = (const float*)d_in[2];
  const float* rw2 = (const float*)d_in[3];
  const float* rb2 = (const float*)d_in[4];
  const float* w1  = (const float*)d_in[5];
  const float* b1  = (const float*)d_in[6];
  const float* w2  = (const float*)d_in[7];
  const float* b2  = (const float*)d_in[8];
  float* out = (float*)d_out;

  k_prep<<<dim3(TOK * EMBD / 1024 + HIDD / 256 + 1), dim3(256), 0, stream>>>(x, rw2);
  k_transpose_all<<<dim3(9 * 1024 + 8 * 1024), dim3(256), 0, stream>>>(rw1, w1, w2);
  // router GEMM1: [8192 x 4096 x 1024], GN=4 (2MB B-group at K=1024)
  gemm256<true, false, false, 4><<<dim3(HIDD / 256, TOK / 256, 1), dim3(512), 0, stream>>>(
      OFF_X16, OFF_RW1T, rb1, OFF_HR, TOK, HIDD, EMBD);
  k_router<<<dim3(TOK), dim3(256), 0, stream>>>(rb2, x);
  k_flag_gemm<<<dim3(HIDD / 64, 8), dim3(256), 0, stream>>>(rw1, rb1);
  k_flag_fix<<<dim3(512), dim3(256), 0, stream>>>(rw2, rb2);
  k_count_scan<<<dim3(1), dim3(1024), 0, stream>>>();
  k_build<<<dim3(2 * TOK / 256), dim3(256), 0, stream>>>();
  // expert GEMM1: grouped [~16384 x 4096 x 1024], A gathered via tokmap, GN=4
  gemm256<true, true, true, 4><<<dim3(HIDD / 256, 2 * TOK / 256, 8), dim3(512), 0, stream>>>(
      OFF_X16, OFF_W1T, b1, OFF_HG, 0, HIDD, EMBD);
  // expert GEMM2: grouped [~16384 x 1024 x 4096], GN=1 (B-panel 2MB at K=4096)
  gemm256<false, true, false, 1><<<dim3(EMBD / 256, 2 * TOK / 256, 8), dim3(512), 0, stream>>>(
      OFF_HG, OFF_W2T, b2, OFF_YG, 0, EMBD, HIDD);
  k_combine<<<dim3(TOK), dim3(256), 0, stream>>>(out);
}